// Round 2
// baseline (924.357 us; speedup 1.0000x reference)
//
#include <hip/hip_runtime.h>
#include <stdint.h>

#define N_TOK 4096
#define CDIM  2048
#define NEXP  8
#define IDIM  1408
#define ISDIM 2816
#define CAP   2048

typedef __attribute__((ext_vector_type(8))) short bf16x8;
typedef __attribute__((ext_vector_type(4))) float f32x4;

#define GLOAD16(gp, lp) __builtin_amdgcn_global_load_lds( \
    (const __attribute__((address_space(1))) void*)(gp),  \
    (__attribute__((address_space(3))) void*)(lp), 16, 0, 0)

__device__ __forceinline__ unsigned short f2bf(float f) {
  union { float f; unsigned u; } c; c.f = f;
  return (unsigned short)((c.u + 0x7FFFu + ((c.u >> 16) & 1u)) >> 16);
}
__device__ __forceinline__ float bf2f(unsigned short h) {
  union { unsigned u; float f; } c; c.u = (unsigned)h << 16;
  return c.f;
}

// bijective XCD chunk-swizzle (m204): blocks dispatched to XCD k get a
// contiguous logical-wg range -> per-XCD L2 holds a small set of B panels.
__device__ __forceinline__ int xcd_swizzle(int orig, int nwg) {
  int q = nwg >> 3, r = nwg & 7;
  int xcd = orig & 7, idx = orig >> 3;
  return (xcd < r ? xcd * (q + 1) : r * (q + 1) + (xcd - r) * q) + idx;
}

// ---------------- fp32 -> bf16 convert ----------------
__global__ __launch_bounds__(256) void cvt_kernel(
    const float* __restrict__ s, unsigned short* __restrict__ d, int n) {
  int i = (blockIdx.x * 256 + threadIdx.x) * 4;
  if (i >= n) return;
  float4 v = *(const float4*)(s + i);
  ushort4 o;
  o.x = f2bf(v.x); o.y = f2bf(v.y); o.z = f2bf(v.z); o.w = f2bf(v.w);
  *(ushort4*)(d + i) = o;
}

// ---------------- routing: logits -> softmax -> top2, build lists ----------------
__global__ __launch_bounds__(64) void routing_kernel(
    const float* __restrict__ x, const float* __restrict__ gw,
    int* __restrict__ counts, int* __restrict__ list,
    int* __restrict__ slot_of, float* __restrict__ wts) {
  const int n = blockIdx.x;
  const int lane = threadIdx.x;
  const float* xr = x + (size_t)n * CDIM;
  float s[NEXP];
#pragma unroll
  for (int e = 0; e < NEXP; e++) s[e] = 0.f;
  for (int c = lane; c < CDIM; c += 64) {
    float xv = xr[c];
#pragma unroll
    for (int e = 0; e < NEXP; e++) s[e] += xv * gw[e * CDIM + c];
  }
#pragma unroll
  for (int e = 0; e < NEXP; e++) {
    float v = s[e];
    for (int o = 32; o > 0; o >>= 1) v += __shfl_down(v, o);
    s[e] = v;
  }
  if (lane == 0) {
    float mx = s[0];
#pragma unroll
    for (int e = 1; e < NEXP; e++) mx = fmaxf(mx, s[e]);
    float p[NEXP], sum = 0.f;
#pragma unroll
    for (int e = 0; e < NEXP; e++) { p[e] = __expf(s[e] - mx); sum += p[e]; }
    int i0 = 0;
#pragma unroll
    for (int e = 1; e < NEXP; e++) if (p[e] > p[i0]) i0 = e;
    int i1 = (i0 == 0) ? 1 : 0;
#pragma unroll
    for (int e = 0; e < NEXP; e++) if (e != i0 && p[e] > p[i1]) i1 = e;
    float inv = 1.f / sum;
    int s0 = atomicAdd(&counts[i0], 1);
    int s1 = atomicAdd(&counts[i1], 1);
    if (s0 < CAP) list[i0 * CAP + s0] = n; else s0 = 0;
    if (s1 < CAP) list[i1 * CAP + s1] = n; else s1 = 0;
    slot_of[n * 2]     = i0 * CAP + s0;
    slot_of[n * 2 + 1] = i1 * CAP + s1;
    wts[n * 2]     = p[i0] * inv;
    wts[n * 2 + 1] = p[i1] * inv;
  }
}

// ---------------- fused gated GEMM: H = silu(A@B1^T) * (A@B2^T), bf16 out ----------------
// BM=128, BN=128, BK=64, 256 threads (4 waves 2x2), wave tile 64x64 (dual acc).
// 1D x-grid (Mt*Nt), M-tile fastest + XCD chunk swizzle.
template <bool GATHER>
__global__ __launch_bounds__(256) void gemm_gated_kernel(
    const unsigned short* __restrict__ A,
    const unsigned short* __restrict__ B1,
    const unsigned short* __restrict__ B2,
    unsigned short* __restrict__ H,
    int Ka, int ldo, int Mt, int Nt,
    const int* __restrict__ list, const int* __restrict__ counts) {
  const int nwg = Mt * Nt;
  const int wg = xcd_swizzle(blockIdx.x, nwg);
  const int mt = wg % Mt, nt = wg / Mt;
  int cnt = 0;
  if (GATHER) {
    const int e = blockIdx.z;
    cnt = counts[e];
    if (cnt > CAP) cnt = CAP;
    if (mt * 128 >= cnt) return;
    B1 += (size_t)e * IDIM * CDIM;
    B2 += (size_t)e * IDIM * CDIM;
    H  += (size_t)e * CAP * IDIM;
    list += e * CAP;
  }
  __shared__ __align__(16) unsigned short As[128 * 64];
  __shared__ __align__(16) unsigned short Bs1[128 * 64];
  __shared__ __align__(16) unsigned short Bs2[128 * 64];

  const int t = threadIdx.x;
  const int wb = t & ~63;

  const unsigned short* aP[4];
#pragma unroll
  for (int j = 0; j < 4; j++) {
    int idx = j * 256 + t;
    int r = idx >> 3, c8 = (idx & 7) * 8;
    int grow;
    if (GATHER) {
      int sr = mt * 128 + r;
      grow = (sr < cnt) ? list[sr] : list[0];
    } else {
      grow = mt * 128 + r;
    }
    aP[j] = A + (size_t)grow * Ka + c8;
  }
  const unsigned short *bP1[4], *bP2[4];
#pragma unroll
  for (int j = 0; j < 4; j++) {
    int idx = j * 256 + t;
    int r = idx >> 3, c8 = (idx & 7) * 8;
    size_t o = (size_t)(nt * 128 + r) * Ka + c8;
    bP1[j] = B1 + o;
    bP2[j] = B2 + o;
  }

  const int lane = t & 63, wid = t >> 6;
  const int wm = wid >> 1, wn = wid & 1;
  const int lrow = lane & 15, lk = (lane >> 4) * 8;
  int aoff[4], boff[4];
#pragma unroll
  for (int m = 0; m < 4; m++) aoff[m] = (wm * 64 + m * 16 + lrow) * 64 + lk;
#pragma unroll
  for (int n = 0; n < 4; n++) boff[n] = (wn * 64 + n * 16 + lrow) * 64 + lk;

  const f32x4 z4 = {0.f, 0.f, 0.f, 0.f};
  f32x4 acc1[4][4], acc2[4][4];
#pragma unroll
  for (int m = 0; m < 4; m++)
#pragma unroll
    for (int n = 0; n < 4; n++) { acc1[m][n] = z4; acc2[m][n] = z4; }

  for (int k0 = 0; k0 < Ka; k0 += 64) {
#pragma unroll
    for (int j = 0; j < 4; j++) {
      GLOAD16(aP[j] + k0, &As[(j * 256 + wb) * 8]);
      GLOAD16(bP1[j] + k0, &Bs1[(j * 256 + wb) * 8]);
      GLOAD16(bP2[j] + k0, &Bs2[(j * 256 + wb) * 8]);
    }
    __syncthreads();
#pragma unroll
    for (int kk = 0; kk < 2; kk++) {
      bf16x8 af[4];
#pragma unroll
      for (int m = 0; m < 4; m++) af[m] = *(const bf16x8*)&As[aoff[m] + kk * 32];
#pragma unroll
      for (int n = 0; n < 4; n++) {
        bf16x8 b1 = *(const bf16x8*)&Bs1[boff[n] + kk * 32];
#pragma unroll
        for (int m = 0; m < 4; m++)
          acc1[m][n] = __builtin_amdgcn_mfma_f32_16x16x32_bf16(af[m], b1, acc1[m][n], 0, 0, 0);
        bf16x8 b2 = *(const bf16x8*)&Bs2[boff[n] + kk * 32];
#pragma unroll
        for (int m = 0; m < 4; m++)
          acc2[m][n] = __builtin_amdgcn_mfma_f32_16x16x32_bf16(af[m], b2, acc2[m][n], 0, 0, 0);
      }
    }
    __syncthreads();
  }

  const int colb = nt * 128 + wn * 64;
  const int rowb = mt * 128 + wm * 64;
#pragma unroll
  for (int m = 0; m < 4; m++)
#pragma unroll
    for (int n = 0; n < 4; n++) {
      int col = colb + n * 16 + lrow;
      int row0 = rowb + m * 16 + (lane >> 4) * 4;
#pragma unroll
      for (int r = 0; r < 4; r++) {
        float z = acc1[m][n][r];
        float g = z / (1.f + __expf(-z));   // silu
        H[(size_t)(row0 + r) * ldo + col] = f2bf(g * acc2[m][n][r]);
      }
    }
}

// ---------------- plain B^T GEMM: Out = A@B^T ----------------
// BM=128, BN=128, BK=64, 256 threads (4 waves 2x2), wave tile 64x64.
template <bool EXPERT, bool OUTF32>
__global__ __launch_bounds__(256) void gemm_bt_kernel(
    const unsigned short* __restrict__ A,
    const unsigned short* __restrict__ B,
    void* __restrict__ OutV,
    int Ka, int ldo, int Mt, int Nt,
    const int* __restrict__ counts,
    size_t strideA, size_t strideB, size_t strideO) {
  const int nwg = Mt * Nt;
  const int wg = xcd_swizzle(blockIdx.x, nwg);
  const int mt = wg % Mt, nt = wg / Mt;
  size_t obase = 0;
  if (EXPERT) {
    const int e = blockIdx.z;
    int cnt = counts[e];
    if (cnt > CAP) cnt = CAP;
    if (mt * 128 >= cnt) return;
    A += (size_t)e * strideA;
    B += (size_t)e * strideB;
    obase = (size_t)e * strideO;
  }
  __shared__ __align__(16) unsigned short As[128 * 64];
  __shared__ __align__(16) unsigned short Bs[128 * 64];

  const int t = threadIdx.x;
  const int wb = t & ~63;
  const unsigned short *aP[4], *bP[4];
#pragma unroll
  for (int j = 0; j < 4; j++) {
    int idx = j * 256 + t;
    int r = idx >> 3, c8 = (idx & 7) * 8;
    aP[j] = A + (size_t)(mt * 128 + r) * Ka + c8;
    bP[j] = B + (size_t)(nt * 128 + r) * Ka + c8;
  }
  const int lane = t & 63, wid = t >> 6;
  const int wm = wid >> 1, wn = wid & 1;
  const int lrow = lane & 15, lk = (lane >> 4) * 8;
  int aoff[4], boff[4];
#pragma unroll
  for (int m = 0; m < 4; m++) aoff[m] = (wm * 64 + m * 16 + lrow) * 64 + lk;
#pragma unroll
  for (int n = 0; n < 4; n++) boff[n] = (wn * 64 + n * 16 + lrow) * 64 + lk;

  const f32x4 z4 = {0.f, 0.f, 0.f, 0.f};
  f32x4 acc[4][4];
#pragma unroll
  for (int m = 0; m < 4; m++)
#pragma unroll
    for (int n = 0; n < 4; n++) acc[m][n] = z4;

  for (int k0 = 0; k0 < Ka; k0 += 64) {
#pragma unroll
    for (int j = 0; j < 4; j++) {
      GLOAD16(aP[j] + k0, &As[(j * 256 + wb) * 8]);
      GLOAD16(bP[j] + k0, &Bs[(j * 256 + wb) * 8]);
    }
    __syncthreads();
#pragma unroll
    for (int kk = 0; kk < 2; kk++) {
      bf16x8 af[4], bfv[4];
#pragma unroll
      for (int m = 0; m < 4; m++) af[m] = *(const bf16x8*)&As[aoff[m] + kk * 32];
#pragma unroll
      for (int n = 0; n < 4; n++) bfv[n] = *(const bf16x8*)&Bs[boff[n] + kk * 32];
#pragma unroll
      for (int m = 0; m < 4; m++)
#pragma unroll
        for (int n = 0; n < 4; n++)
          acc[m][n] = __builtin_amdgcn_mfma_f32_16x16x32_bf16(af[m], bfv[n], acc[m][n], 0, 0, 0);
    }
    __syncthreads();
  }

  const int colb = nt * 128 + wn * 64;
  const int rowb = mt * 128 + wm * 64;
#pragma unroll
  for (int m = 0; m < 4; m++)
#pragma unroll
    for (int n = 0; n < 4; n++) {
      int col = colb + n * 16 + lrow;
      int row0 = rowb + m * 16 + (lane >> 4) * 4;
#pragma unroll
      for (int r = 0; r < 4; r++) {
        if (OUTF32)
          ((float*)OutV)[obase + (size_t)(row0 + r) * ldo + col] = acc[m][n][r];
        else
          ((unsigned short*)OutV)[obase + (size_t)(row0 + r) * ldo + col] = f2bf(acc[m][n][r]);
      }
    }
}

// ---------------- weighted expert combine into y ----------------
__global__ __launch_bounds__(256) void combine_kernel(
    float* __restrict__ y, const unsigned short* __restrict__ eo,
    const int* __restrict__ slot_of, const float* __restrict__ wts) {
  int idx = blockIdx.x * 256 + threadIdx.x;
  int n = idx >> 9;            // C/4 = 512 chunks per token
  int c = (idx & 511) * 4;
  float* yp = y + (size_t)n * CDIM + c;
  float4 v = *(float4*)yp;
#pragma unroll
  for (int k = 0; k < 2; k++) {
    int slot = slot_of[n * 2 + k];
    float w = wts[n * 2 + k];
    ushort4 h = *(const ushort4*)(eo + (size_t)slot * CDIM + c);
    v.x += w * bf2f(h.x);
    v.y += w * bf2f(h.y);
    v.z += w * bf2f(h.z);
    v.w += w * bf2f(h.w);
  }
  *(float4*)yp = v;
}

extern "C" void kernel_launch(void* const* d_in, const int* in_sizes, int n_in,
                              void* d_out, int out_size, void* d_ws, size_t ws_size,
                              hipStream_t stream) {
  const float* x   = (const float*)d_in[0];
  const float* gw  = (const float*)d_in[1];
  const float* w1  = (const float*)d_in[2];
  const float* w2  = (const float*)d_in[3];
  const float* w3  = (const float*)d_in[4];
  const float* sw1 = (const float*)d_in[5];
  const float* sw2 = (const float*)d_in[6];
  const float* sw3 = (const float*)d_in[7];
  float* y = (float*)d_out;

  char* ws = (char*)d_ws;
  size_t off = 0;
  auto alloc = [&](size_t b) -> void* {
    void* p = ws + off;
    off += (b + 255) & ~(size_t)255;
    return p;
  };
  unsigned short* xb   = (unsigned short*)alloc((size_t)N_TOK * CDIM * 2);
  unsigned short* w1b  = (unsigned short*)alloc((size_t)NEXP * IDIM * CDIM * 2);
  unsigned short* w2b  = (unsigned short*)alloc((size_t)NEXP * IDIM * CDIM * 2);
  unsigned short* w3b  = (unsigned short*)alloc((size_t)NEXP * CDIM * IDIM * 2);
  unsigned short* sw1b = (unsigned short*)alloc((size_t)ISDIM * CDIM * 2);
  unsigned short* sw2b = (unsigned short*)alloc((size_t)ISDIM * CDIM * 2);
  unsigned short* sw3b = (unsigned short*)alloc((size_t)CDIM * ISDIM * 2);
  unsigned short* hs   = (unsigned short*)alloc((size_t)N_TOK * ISDIM * 2);
  unsigned short* he   = (unsigned short*)alloc((size_t)NEXP * CAP * IDIM * 2);
  unsigned short* eo   = (unsigned short*)alloc((size_t)NEXP * CAP * CDIM * 2);
  int*   counts  = (int*)alloc(NEXP * 4);
  int*   list    = (int*)alloc((size_t)NEXP * CAP * 4);
  int*   slot_of = (int*)alloc((size_t)N_TOK * 2 * 4);
  float* wtsb    = (float*)alloc((size_t)N_TOK * 2 * 4);

  hipMemsetAsync(counts, 0, NEXP * 4, stream);
  routing_kernel<<<N_TOK, 64, 0, stream>>>(x, gw, counts, list, slot_of, wtsb);

  auto cvt = [&](const float* s, unsigned short* d, size_t n) {
    cvt_kernel<<<(int)(n / 1024), 256, 0, stream>>>(s, d, (int)n);
  };
  cvt(x,   xb,   (size_t)N_TOK * CDIM);
  cvt(w1,  w1b,  (size_t)NEXP * IDIM * CDIM);
  cvt(w2,  w2b,  (size_t)NEXP * IDIM * CDIM);
  cvt(w3,  w3b,  (size_t)NEXP * CDIM * IDIM);
  cvt(sw1, sw1b, (size_t)ISDIM * CDIM);
  cvt(sw2, sw2b, (size_t)ISDIM * CDIM);
  cvt(sw3, sw3b, (size_t)CDIM * ISDIM);

  // shared expert gated MLP: hs = silu(x@sw1^T)*(x@sw2^T)   [4096 x 2816]
  gemm_gated_kernel<false><<<dim3(32 * 22, 1, 1), 256, 0, stream>>>(
      xb, sw1b, sw2b, hs, CDIM, ISDIM, 32, 22, nullptr, nullptr);
  // expert gated MLP (gathered): he = silu(xg@w1^T)*(xg@w2^T) [8 x CAP x 1408]
  gemm_gated_kernel<true><<<dim3(16 * 11, 1, NEXP), 256, 0, stream>>>(
      xb, w1b, w2b, he, CDIM, IDIM, 16, 11, list, counts);
  // shared proj: y = hs@sw3^T (fp32, direct to output)
  gemm_bt_kernel<false, true><<<dim3(32 * 16, 1, 1), 256, 0, stream>>>(
      hs, sw3b, y, ISDIM, CDIM, 32, 16, nullptr, 0, 0, 0);
  // expert proj: eo = he@w3^T (bf16)
  gemm_bt_kernel<true, false><<<dim3(16 * 16, 1, NEXP), 256, 0, stream>>>(
      he, w3b, eo, IDIM, CDIM, 16, 16, counts,
      (size_t)CAP * IDIM, (size_t)CDIM * IDIM, (size_t)CAP * CDIM);
  // y += sum_k w_k * eo[slot_k]
  combine_kernel<<<(N_TOK * (CDIM / 4)) / 256, 256, 0, stream>>>(y, eo, slot_of, wtsb);
}

// Round 3
// 806.472 us; speedup vs baseline: 1.1462x; 1.1462x over previous
//
#include <hip/hip_runtime.h>
#include <stdint.h>

#define N_TOK 4096
#define CDIM  2048
#define NEXP  8
#define IDIM  1408
#define ISDIM 2816
#define CAP   2048

typedef __attribute__((ext_vector_type(8))) short bf16x8;
typedef __attribute__((ext_vector_type(4))) float f32x4;

#define GLOAD16(gp, lp) __builtin_amdgcn_global_load_lds( \
    (const __attribute__((address_space(1))) void*)(gp),  \
    (__attribute__((address_space(3))) void*)(lp), 16, 0, 0)

__device__ __forceinline__ unsigned short f2bf(float f) {
  union { float f; unsigned u; } c; c.f = f;
  return (unsigned short)((c.u + 0x7FFFu + ((c.u >> 16) & 1u)) >> 16);
}
__device__ __forceinline__ float bf2f(unsigned short h) {
  union { unsigned u; float f; } c; c.u = (unsigned)h << 16;
  return c.f;
}

// bijective XCD chunk-swizzle (m204): blocks dispatched to XCD k get a
// contiguous logical-wg range -> per-XCD L2 holds a small set of B panels.
__device__ __forceinline__ int xcd_swizzle(int orig, int nwg) {
  int q = nwg >> 3, r = nwg & 7;
  int xcd = orig & 7, idx = orig >> 3;
  return (xcd < r ? xcd * (q + 1) : r * (q + 1) + (xcd - r) * q) + idx;
}

// ---------------- fp32 -> bf16 convert ----------------
__global__ __launch_bounds__(256) void cvt_kernel(
    const float* __restrict__ s, unsigned short* __restrict__ d, int n) {
  int i = (blockIdx.x * 256 + threadIdx.x) * 4;
  if (i >= n) return;
  float4 v = *(const float4*)(s + i);
  ushort4 o;
  o.x = f2bf(v.x); o.y = f2bf(v.y); o.z = f2bf(v.z); o.w = f2bf(v.w);
  *(ushort4*)(d + i) = o;
}

// ---------------- routing: logits -> softmax -> top2, build lists ----------------
__global__ __launch_bounds__(64) void routing_kernel(
    const float* __restrict__ x, const float* __restrict__ gw,
    int* __restrict__ counts, int* __restrict__ list,
    int* __restrict__ slot_of, float* __restrict__ wts) {
  const int n = blockIdx.x;
  const int lane = threadIdx.x;
  const float* xr = x + (size_t)n * CDIM;
  float s[NEXP];
#pragma unroll
  for (int e = 0; e < NEXP; e++) s[e] = 0.f;
  for (int c = lane; c < CDIM; c += 64) {
    float xv = xr[c];
#pragma unroll
    for (int e = 0; e < NEXP; e++) s[e] += xv * gw[e * CDIM + c];
  }
#pragma unroll
  for (int e = 0; e < NEXP; e++) {
    float v = s[e];
    for (int o = 32; o > 0; o >>= 1) v += __shfl_down(v, o);
    s[e] = v;
  }
  if (lane == 0) {
    float mx = s[0];
#pragma unroll
    for (int e = 1; e < NEXP; e++) mx = fmaxf(mx, s[e]);
    float p[NEXP], sum = 0.f;
#pragma unroll
    for (int e = 0; e < NEXP; e++) { p[e] = __expf(s[e] - mx); sum += p[e]; }
    int i0 = 0;
#pragma unroll
    for (int e = 1; e < NEXP; e++) if (p[e] > p[i0]) i0 = e;
    int i1 = (i0 == 0) ? 1 : 0;
#pragma unroll
    for (int e = 0; e < NEXP; e++) if (e != i0 && p[e] > p[i1]) i1 = e;
    float inv = 1.f / sum;
    int s0 = atomicAdd(&counts[i0], 1);
    int s1 = atomicAdd(&counts[i1], 1);
    if (s0 < CAP) list[i0 * CAP + s0] = n; else s0 = 0;
    if (s1 < CAP) list[i1 * CAP + s1] = n; else s1 = 0;
    slot_of[n * 2]     = i0 * CAP + s0;
    slot_of[n * 2 + 1] = i1 * CAP + s1;
    wts[n * 2]     = p[i0] * inv;
    wts[n * 2 + 1] = p[i1] * inv;
  }
}

// ---------------- fused gated GEMM: H = silu(A@B1^T) * (A@B2^T), bf16 out ----------------
// BM=128, BN=64, BK=64, 256 threads (4 waves, 2x2), wave tile 64x32, dual acc.
// 1D x-grid (Mt*Nt), M-tile fastest + XCD chunk swizzle.
template <bool GATHER>
__global__ __launch_bounds__(256) void gemm_gated_kernel(
    const unsigned short* __restrict__ A,
    const unsigned short* __restrict__ B1,
    const unsigned short* __restrict__ B2,
    unsigned short* __restrict__ H,
    int Ka, int ldo, int Mt, int Nt,
    const int* __restrict__ list, const int* __restrict__ counts) {
  const int nwg = Mt * Nt;
  const int wg = xcd_swizzle(blockIdx.x, nwg);
  const int mt = wg % Mt, nt = wg / Mt;
  int cnt = 0;
  if (GATHER) {
    const int e = blockIdx.z;
    cnt = counts[e];
    if (cnt > CAP) cnt = CAP;
    if (mt * 128 >= cnt) return;
    B1 += (size_t)e * IDIM * CDIM;
    B2 += (size_t)e * IDIM * CDIM;
    H  += (size_t)e * CAP * IDIM;
    list += e * CAP;
  }
  __shared__ __align__(16) unsigned short As[128 * 64];
  __shared__ __align__(16) unsigned short Bs1[64 * 64];
  __shared__ __align__(16) unsigned short Bs2[64 * 64];

  const int t = threadIdx.x;
  const int wb = t & ~63;

  const unsigned short* aP[4];
#pragma unroll
  for (int j = 0; j < 4; j++) {
    int idx = j * 256 + t;
    int r = idx >> 3, c8 = (idx & 7) * 8;
    int grow;
    if (GATHER) {
      int sr = mt * 128 + r;
      grow = (sr < cnt) ? list[sr] : list[0];
    } else {
      grow = mt * 128 + r;
    }
    aP[j] = A + (size_t)grow * Ka + c8;
  }
  const unsigned short *bP1[2], *bP2[2];
#pragma unroll
  for (int j = 0; j < 2; j++) {
    int idx = j * 256 + t;
    int r = idx >> 3, c8 = (idx & 7) * 8;
    size_t o = (size_t)(nt * 64 + r) * Ka + c8;
    bP1[j] = B1 + o;
    bP2[j] = B2 + o;
  }

  const int lane = t & 63, wid = t >> 6;
  const int wm = wid >> 1, wn = wid & 1;
  const int lrow = lane & 15, lk = (lane >> 4) * 8;
  int aoff[4], boff[2];
#pragma unroll
  for (int m = 0; m < 4; m++) aoff[m] = (wm * 64 + m * 16 + lrow) * 64 + lk;
#pragma unroll
  for (int n = 0; n < 2; n++) boff[n] = (wn * 32 + n * 16 + lrow) * 64 + lk;

  const f32x4 z4 = {0.f, 0.f, 0.f, 0.f};
  f32x4 acc1[4][2], acc2[4][2];
#pragma unroll
  for (int m = 0; m < 4; m++)
#pragma unroll
    for (int n = 0; n < 2; n++) { acc1[m][n] = z4; acc2[m][n] = z4; }

  for (int k0 = 0; k0 < Ka; k0 += 64) {
#pragma unroll
    for (int j = 0; j < 4; j++) GLOAD16(aP[j] + k0, &As[(j * 256 + wb) * 8]);
#pragma unroll
    for (int j = 0; j < 2; j++) {
      GLOAD16(bP1[j] + k0, &Bs1[(j * 256 + wb) * 8]);
      GLOAD16(bP2[j] + k0, &Bs2[(j * 256 + wb) * 8]);
    }
    __syncthreads();
#pragma unroll
    for (int kk = 0; kk < 2; kk++) {
      bf16x8 af[4], b1f[2], b2f[2];
#pragma unroll
      for (int m = 0; m < 4; m++) af[m] = *(const bf16x8*)&As[aoff[m] + kk * 32];
#pragma unroll
      for (int n = 0; n < 2; n++) {
        b1f[n] = *(const bf16x8*)&Bs1[boff[n] + kk * 32];
        b2f[n] = *(const bf16x8*)&Bs2[boff[n] + kk * 32];
      }
#pragma unroll
      for (int m = 0; m < 4; m++)
#pragma unroll
        for (int n = 0; n < 2; n++) {
          acc1[m][n] = __builtin_amdgcn_mfma_f32_16x16x32_bf16(af[m], b1f[n], acc1[m][n], 0, 0, 0);
          acc2[m][n] = __builtin_amdgcn_mfma_f32_16x16x32_bf16(af[m], b2f[n], acc2[m][n], 0, 0, 0);
        }
    }
    __syncthreads();
  }

  const int colb = nt * 64 + wn * 32;
  const int rowb = mt * 128 + wm * 64;
#pragma unroll
  for (int m = 0; m < 4; m++)
#pragma unroll
    for (int n = 0; n < 2; n++) {
      int col = colb + n * 16 + lrow;
      int row0 = rowb + m * 16 + (lane >> 4) * 4;
#pragma unroll
      for (int r = 0; r < 4; r++) {
        float z = acc1[m][n][r];
        float g = z / (1.f + __expf(-z));   // silu
        H[(size_t)(row0 + r) * ldo + col] = f2bf(g * acc2[m][n][r]);
      }
    }
}

// ---------------- plain B^T GEMM: Out = A@B^T ----------------
// BM=128, BN=128, BK=64, 256 threads (4 waves 2x2), wave tile 64x64.
template <bool EXPERT, bool OUTF32>
__global__ __launch_bounds__(256) void gemm_bt_kernel(
    const unsigned short* __restrict__ A,
    const unsigned short* __restrict__ B,
    void* __restrict__ OutV,
    int Ka, int ldo, int Mt, int Nt,
    const int* __restrict__ counts,
    size_t strideA, size_t strideB, size_t strideO) {
  const int nwg = Mt * Nt;
  const int wg = xcd_swizzle(blockIdx.x, nwg);
  const int mt = wg % Mt, nt = wg / Mt;
  size_t obase = 0;
  if (EXPERT) {
    const int e = blockIdx.z;
    int cnt = counts[e];
    if (cnt > CAP) cnt = CAP;
    if (mt * 128 >= cnt) return;
    A += (size_t)e * strideA;
    B += (size_t)e * strideB;
    obase = (size_t)e * strideO;
  }
  __shared__ __align__(16) unsigned short As[128 * 64];
  __shared__ __align__(16) unsigned short Bs[128 * 64];

  const int t = threadIdx.x;
  const int wb = t & ~63;
  const unsigned short *aP[4], *bP[4];
#pragma unroll
  for (int j = 0; j < 4; j++) {
    int idx = j * 256 + t;
    int r = idx >> 3, c8 = (idx & 7) * 8;
    aP[j] = A + (size_t)(mt * 128 + r) * Ka + c8;
    bP[j] = B + (size_t)(nt * 128 + r) * Ka + c8;
  }
  const int lane = t & 63, wid = t >> 6;
  const int wm = wid >> 1, wn = wid & 1;
  const int lrow = lane & 15, lk = (lane >> 4) * 8;
  int aoff[4], boff[4];
#pragma unroll
  for (int m = 0; m < 4; m++) aoff[m] = (wm * 64 + m * 16 + lrow) * 64 + lk;
#pragma unroll
  for (int n = 0; n < 4; n++) boff[n] = (wn * 64 + n * 16 + lrow) * 64 + lk;

  const f32x4 z4 = {0.f, 0.f, 0.f, 0.f};
  f32x4 acc[4][4];
#pragma unroll
  for (int m = 0; m < 4; m++)
#pragma unroll
    for (int n = 0; n < 4; n++) acc[m][n] = z4;

  for (int k0 = 0; k0 < Ka; k0 += 64) {
#pragma unroll
    for (int j = 0; j < 4; j++) {
      GLOAD16(aP[j] + k0, &As[(j * 256 + wb) * 8]);
      GLOAD16(bP[j] + k0, &Bs[(j * 256 + wb) * 8]);
    }
    __syncthreads();
#pragma unroll
    for (int kk = 0; kk < 2; kk++) {
      bf16x8 af[4], bfv[4];
#pragma unroll
      for (int m = 0; m < 4; m++) af[m] = *(const bf16x8*)&As[aoff[m] + kk * 32];
#pragma unroll
      for (int n = 0; n < 4; n++) bfv[n] = *(const bf16x8*)&Bs[boff[n] + kk * 32];
#pragma unroll
      for (int m = 0; m < 4; m++)
#pragma unroll
        for (int n = 0; n < 4; n++)
          acc[m][n] = __builtin_amdgcn_mfma_f32_16x16x32_bf16(af[m], bfv[n], acc[m][n], 0, 0, 0);
    }
    __syncthreads();
  }

  const int colb = nt * 128 + wn * 64;
  const int rowb = mt * 128 + wm * 64;
#pragma unroll
  for (int m = 0; m < 4; m++)
#pragma unroll
    for (int n = 0; n < 4; n++) {
      int col = colb + n * 16 + lrow;
      int row0 = rowb + m * 16 + (lane >> 4) * 4;
#pragma unroll
      for (int r = 0; r < 4; r++) {
        if (OUTF32)
          ((float*)OutV)[obase + (size_t)(row0 + r) * ldo + col] = acc[m][n][r];
        else
          ((unsigned short*)OutV)[obase + (size_t)(row0 + r) * ldo + col] = f2bf(acc[m][n][r]);
      }
    }
}

// ---------------- weighted expert combine into y ----------------
__global__ __launch_bounds__(256) void combine_kernel(
    float* __restrict__ y, const unsigned short* __restrict__ eo,
    const int* __restrict__ slot_of, const float* __restrict__ wts) {
  int idx = blockIdx.x * 256 + threadIdx.x;
  int n = idx >> 9;            // C/4 = 512 chunks per token
  int c = (idx & 511) * 4;
  float* yp = y + (size_t)n * CDIM + c;
  float4 v = *(float4*)yp;
#pragma unroll
  for (int k = 0; k < 2; k++) {
    int slot = slot_of[n * 2 + k];
    float w = wts[n * 2 + k];
    ushort4 h = *(const ushort4*)(eo + (size_t)slot * CDIM + c);
    v.x += w * bf2f(h.x);
    v.y += w * bf2f(h.y);
    v.z += w * bf2f(h.z);
    v.w += w * bf2f(h.w);
  }
  *(float4*)yp = v;
}

extern "C" void kernel_launch(void* const* d_in, const int* in_sizes, int n_in,
                              void* d_out, int out_size, void* d_ws, size_t ws_size,
                              hipStream_t stream) {
  const float* x   = (const float*)d_in[0];
  const float* gw  = (const float*)d_in[1];
  const float* w1  = (const float*)d_in[2];
  const float* w2  = (const float*)d_in[3];
  const float* w3  = (const float*)d_in[4];
  const float* sw1 = (const float*)d_in[5];
  const float* sw2 = (const float*)d_in[6];
  const float* sw3 = (const float*)d_in[7];
  float* y = (float*)d_out;

  char* ws = (char*)d_ws;
  size_t off = 0;
  auto alloc = [&](size_t b) -> void* {
    void* p = ws + off;
    off += (b + 255) & ~(size_t)255;
    return p;
  };
  unsigned short* xb   = (unsigned short*)alloc((size_t)N_TOK * CDIM * 2);
  unsigned short* w1b  = (unsigned short*)alloc((size_t)NEXP * IDIM * CDIM * 2);
  unsigned short* w2b  = (unsigned short*)alloc((size_t)NEXP * IDIM * CDIM * 2);
  unsigned short* w3b  = (unsigned short*)alloc((size_t)NEXP * CDIM * IDIM * 2);
  unsigned short* sw1b = (unsigned short*)alloc((size_t)ISDIM * CDIM * 2);
  unsigned short* sw2b = (unsigned short*)alloc((size_t)ISDIM * CDIM * 2);
  unsigned short* sw3b = (unsigned short*)alloc((size_t)CDIM * ISDIM * 2);
  unsigned short* hs   = (unsigned short*)alloc((size_t)N_TOK * ISDIM * 2);
  unsigned short* he   = (unsigned short*)alloc((size_t)NEXP * CAP * IDIM * 2);
  unsigned short* eo   = (unsigned short*)alloc((size_t)NEXP * CAP * CDIM * 2);
  int*   counts  = (int*)alloc(NEXP * 4);
  int*   list    = (int*)alloc((size_t)NEXP * CAP * 4);
  int*   slot_of = (int*)alloc((size_t)N_TOK * 2 * 4);
  float* wtsb    = (float*)alloc((size_t)N_TOK * 2 * 4);

  hipMemsetAsync(counts, 0, NEXP * 4, stream);
  routing_kernel<<<N_TOK, 64, 0, stream>>>(x, gw, counts, list, slot_of, wtsb);

  auto cvt = [&](const float* s, unsigned short* d, size_t n) {
    cvt_kernel<<<(int)(n / 1024), 256, 0, stream>>>(s, d, (int)n);
  };
  cvt(x,   xb,   (size_t)N_TOK * CDIM);
  cvt(w1,  w1b,  (size_t)NEXP * IDIM * CDIM);
  cvt(w2,  w2b,  (size_t)NEXP * IDIM * CDIM);
  cvt(w3,  w3b,  (size_t)NEXP * CDIM * IDIM);
  cvt(sw1, sw1b, (size_t)ISDIM * CDIM);
  cvt(sw2, sw2b, (size_t)ISDIM * CDIM);
  cvt(sw3, sw3b, (size_t)CDIM * ISDIM);

  // shared expert gated MLP: hs = silu(x@sw1^T)*(x@sw2^T)   [4096 x 2816]
  gemm_gated_kernel<false><<<dim3(32 * 44, 1, 1), 256, 0, stream>>>(
      xb, sw1b, sw2b, hs, CDIM, ISDIM, 32, 44, nullptr, nullptr);
  // expert gated MLP (gathered): he = silu(xg@w1^T)*(xg@w2^T) [8 x CAP x 1408]
  gemm_gated_kernel<true><<<dim3(16 * 22, 1, NEXP), 256, 0, stream>>>(
      xb, w1b, w2b, he, CDIM, IDIM, 16, 22, list, counts);
  // shared proj: y = hs@sw3^T (fp32, direct to output)
  gemm_bt_kernel<false, true><<<dim3(32 * 16, 1, 1), 256, 0, stream>>>(
      hs, sw3b, y, ISDIM, CDIM, 32, 16, nullptr, 0, 0, 0);
  // expert proj: eo = he@w3^T (bf16)
  gemm_bt_kernel<true, false><<<dim3(16 * 16, 1, NEXP), 256, 0, stream>>>(
      he, w3b, eo, IDIM, CDIM, 16, 16, counts,
      (size_t)CAP * IDIM, (size_t)CDIM * IDIM, (size_t)CAP * CDIM);
  // y += sum_k w_k * eo[slot_k]
  combine_kernel<<<(N_TOK * (CDIM / 4)) / 256, 256, 0, stream>>>(y, eo, slot_of, wtsb);
}

// Round 4
// 686.045 us; speedup vs baseline: 1.3474x; 1.1755x over previous
//
#include <hip/hip_runtime.h>
#include <stdint.h>

#define N_TOK 4096
#define CDIM  2048
#define NEXP  8
#define IDIM  1408
#define ISDIM 2816
#define CAP   2048
#define ICAT  2816   // [w1;w2] rows per expert
#define SCAT  5632   // [sw1;sw2] rows

typedef __attribute__((ext_vector_type(8))) short bf16x8;
typedef __attribute__((ext_vector_type(4))) float f32x4;

#define GLOAD16(gp, lp) __builtin_amdgcn_global_load_lds( \
    (const __attribute__((address_space(1))) void*)(gp),  \
    (__attribute__((address_space(3))) void*)(lp), 16, 0, 0)

__device__ __forceinline__ unsigned short f2bf(float f) {
  union { float f; unsigned u; } c; c.f = f;
  return (unsigned short)((c.u + 0x7FFFu + ((c.u >> 16) & 1u)) >> 16);
}
__device__ __forceinline__ float bf2f(unsigned short h) {
  union { unsigned u; float f; } c; c.u = (unsigned)h << 16;
  return c.f;
}

__device__ __forceinline__ int xcd_swizzle(int orig, int nwg) {
  int q = nwg >> 3, r = nwg & 7;
  int xcd = orig & 7, idx = orig >> 3;
  return (xcd < r ? xcd * (q + 1) : r * (q + 1) + (xcd - r) * q) + idx;
}

// ---------------- fp32 -> bf16 convert (chunked for concat layouts) ----------------
__global__ __launch_bounds__(256) void cvt_kernel(
    const float* __restrict__ s, unsigned short* __restrict__ d,
    int chunkElems, size_t dstOff, size_t dstStride) {
  size_t z = blockIdx.z;
  size_t i = (size_t)blockIdx.x * 1024 + (size_t)threadIdx.x * 4;
  if (i >= (size_t)chunkElems) return;
  float4 v = *(const float4*)(s + z * chunkElems + i);
  ushort4 o;
  o.x = f2bf(v.x); o.y = f2bf(v.y); o.z = f2bf(v.z); o.w = f2bf(v.w);
  *(ushort4*)(d + z * dstStride + dstOff + i) = o;
}

// ---------------- routing ----------------
__global__ __launch_bounds__(64) void routing_kernel(
    const float* __restrict__ x, const float* __restrict__ gw,
    int* __restrict__ counts, int* __restrict__ list,
    int* __restrict__ slot_of, float* __restrict__ wts) {
  const int n = blockIdx.x;
  const int lane = threadIdx.x;
  const float* xr = x + (size_t)n * CDIM;
  float s[NEXP];
#pragma unroll
  for (int e = 0; e < NEXP; e++) s[e] = 0.f;
  for (int c = lane; c < CDIM; c += 64) {
    float xv = xr[c];
#pragma unroll
    for (int e = 0; e < NEXP; e++) s[e] += xv * gw[e * CDIM + c];
  }
#pragma unroll
  for (int e = 0; e < NEXP; e++) {
    float v = s[e];
    for (int o = 32; o > 0; o >>= 1) v += __shfl_down(v, o);
    s[e] = v;
  }
  if (lane == 0) {
    float mx = s[0];
#pragma unroll
    for (int e = 1; e < NEXP; e++) mx = fmaxf(mx, s[e]);
    float p[NEXP], sum = 0.f;
#pragma unroll
    for (int e = 0; e < NEXP; e++) { p[e] = __expf(s[e] - mx); sum += p[e]; }
    int i0 = 0;
#pragma unroll
    for (int e = 1; e < NEXP; e++) if (p[e] > p[i0]) i0 = e;
    int i1 = (i0 == 0) ? 1 : 0;
#pragma unroll
    for (int e = 0; e < NEXP; e++) if (e != i0 && p[e] > p[i1]) i1 = e;
    float inv = 1.f / sum;
    int s0 = atomicAdd(&counts[i0], 1);
    int s1 = atomicAdd(&counts[i1], 1);
    if (s0 < CAP) list[i0 * CAP + s0] = n; else s0 = 0;
    if (s1 < CAP) list[i1 * CAP + s1] = n; else s1 = 0;
    slot_of[n * 2]     = i0 * CAP + s0;
    slot_of[n * 2 + 1] = i1 * CAP + s1;
    wts[n * 2]     = p[i0] * inv;
    wts[n * 2 + 1] = p[i1] * inv;
  }
}

// ---------------- unified deep-pipelined GEMM: Out = A @ B^T ----------------
// 256x256 tile, BK=64, 512 threads (8 waves, 2M x 4N), per-wave 128x64.
// Double-buffered LDS (128 KiB), 2-tile prefetch, counted vmcnt(8),
// raw s_barrier, T2 XOR-swizzle (linear gload dest + pre-swizzled source).
// PHASE 1: fc.  z<4: shared quadrants (xb @ swcat^T -> hsp).
//               z>=4: expert e=z-4 gathered (xb[list] @ wcat[e]^T -> hep[e]).
// PHASE 2: proj. z<2: shared halves (hs @ sw3^T -> ysf, fp32).
//               z>=2: expert e=z-2 (he[e] @ w3[e]^T -> eo[e], bf16).
template <int PHASE>
__global__ __launch_bounds__(512) void moe_gemm(
    const unsigned short* __restrict__ xb,
    const unsigned short* __restrict__ swcat,
    const unsigned short* __restrict__ wcat,
    unsigned short* __restrict__ hsp,
    unsigned short* __restrict__ hep,
    const unsigned short* __restrict__ hs,
    const unsigned short* __restrict__ sw3b,
    const unsigned short* __restrict__ he,
    const unsigned short* __restrict__ w3b,
    float* __restrict__ ysf,
    unsigned short* __restrict__ eo,
    const int* __restrict__ list,
    const int* __restrict__ counts) {
  const int z = blockIdx.z;
  const unsigned short *A, *B;
  unsigned short* O = nullptr;
  float* Of = nullptr;
  int Ka, ldo;
  int cnt = 1 << 30;
  const int* lst = nullptr;
  int Mt, Nt;
  if (PHASE == 1) {
    Mt = 8; Nt = 11; Ka = CDIM;
    if (z < 4) {
      int zm = z >> 1, zn = z & 1;
      A = xb + (size_t)zm * 2048 * CDIM;
      B = swcat + (size_t)zn * ISDIM * CDIM;
      O = hsp + (size_t)zm * 2048 * SCAT + (size_t)zn * ISDIM;
      ldo = SCAT;
    } else {
      int e = z - 4;
      cnt = counts[e]; if (cnt > CAP) cnt = CAP;
      lst = list + e * CAP;
      A = xb;
      B = wcat + (size_t)e * ICAT * CDIM;
      O = hep + (size_t)e * CAP * ICAT;
      ldo = ICAT;
    }
  } else {
    Mt = 8; Nt = 8;
    if (z < 2) {
      Ka = ISDIM;
      A = hs + (size_t)z * 2048 * ISDIM;
      B = sw3b;
      Of = ysf + (size_t)z * 2048 * CDIM;
      ldo = CDIM;
    } else {
      int e = z - 2;
      cnt = counts[e]; if (cnt > CAP) cnt = CAP;
      Ka = IDIM;
      A = he + (size_t)e * CAP * IDIM;
      B = w3b + (size_t)e * CDIM * IDIM;
      O = eo + (size_t)e * CAP * CDIM;
      ldo = CDIM;
    }
  }
  const int wg = xcd_swizzle(blockIdx.x, Mt * Nt);
  const int mt = wg % Mt, nt = wg / Mt;
  if (mt * 256 >= cnt) return;

  __shared__ __align__(16) char aLds[2 * 32768];
  __shared__ __align__(16) char bLds[2 * 32768];

  const int tid = threadIdx.x;
  // ---- staging: thread covers rows j*64 + (tid>>3), 16B chunk (tid&7)*16,
  //      source col pre-swizzled so a LINEAR LDS write + swizzled read match.
  const int srow = tid >> 3;
  const int scol = ((tid & 7) << 4) ^ ((srow & 7) << 4);
  const char* aSrc[4];
  const char* bSrc[4];
#pragma unroll
  for (int j = 0; j < 4; j++) {
    int ar = mt * 256 + j * 64 + srow;
    if (PHASE == 1 && z >= 4) ar = (ar < cnt) ? lst[ar] : lst[0];
    aSrc[j] = (const char*)A + (size_t)ar * Ka * 2 + scol;
    int br = nt * 256 + j * 64 + srow;
    bSrc[j] = (const char*)B + (size_t)br * Ka * 2 + scol;
  }

  auto stage = [&](int bufsel, int kt) {
    size_t kb = (size_t)kt * 128;
    char* ad = aLds + bufsel * 32768 + tid * 16;
    char* bd = bLds + bufsel * 32768 + tid * 16;
#pragma unroll
    for (int j = 0; j < 4; j++) {
      GLOAD16(aSrc[j] + kb, ad + j * 8192);
      GLOAD16(bSrc[j] + kb, bd + j * 8192);
    }
  };

  const int lane = tid & 63, wid = tid >> 6;
  const int wr = wid >> 2, wc = wid & 3;       // 2 x 4 wave grid
  const int lrow = lane & 15;
  const int klane = (lane >> 4) << 4;          // 0,16,32,48 (bytes)
  const int ar0 = wr * 128 + lrow;
  const int aOff0 = ar0 * 128 + (klane ^ ((ar0 & 7) << 4));
  const int br0 = wc * 64 + lrow;
  const int bOff0 = br0 * 128 + (klane ^ ((br0 & 7) << 4));

  f32x4 acc[8][4];
#pragma unroll
  for (int mf = 0; mf < 8; mf++)
#pragma unroll
    for (int nf = 0; nf < 4; nf++) acc[mf][nf] = (f32x4){0.f, 0.f, 0.f, 0.f};

  stage(0, 0);
  stage(1, 1);
  const int ntk = Ka >> 6;
  for (int t = 0; t < ntk; t++) {
    const char* ab = aLds + (t & 1) * 32768;
    const char* bb = bLds + (t & 1) * 32768;
    if (t == ntk - 1) asm volatile("s_waitcnt vmcnt(0)" ::: "memory");
    else              asm volatile("s_waitcnt vmcnt(8)" ::: "memory");
    __builtin_amdgcn_s_barrier();
#pragma unroll
    for (int kk = 0; kk < 2; kk++) {
      const char* a0 = ab + (aOff0 ^ (kk << 6));
      const char* b0 = bb + (bOff0 ^ (kk << 6));
      bf16x8 af[8], bfr[4];
#pragma unroll
      for (int mf = 0; mf < 8; mf++) af[mf] = *(const bf16x8*)(a0 + mf * 2048);
#pragma unroll
      for (int nf = 0; nf < 4; nf++) bfr[nf] = *(const bf16x8*)(b0 + nf * 2048);
#pragma unroll
      for (int nf = 0; nf < 4; nf++)
#pragma unroll
        for (int mf = 0; mf < 8; mf++)
          acc[mf][nf] = __builtin_amdgcn_mfma_f32_16x16x32_bf16(af[mf], bfr[nf], acc[mf][nf], 0, 0, 0);
    }
    asm volatile("s_waitcnt lgkmcnt(0)" ::: "memory");
    __builtin_amdgcn_s_barrier();
    if (t + 2 < ntk) stage(t & 1, t + 2);
  }

  const int rowb = mt * 256 + wr * 128;
  const int colb = nt * 256 + wc * 64;
  const int r4 = (lane >> 4) * 4;
#pragma unroll
  for (int mf = 0; mf < 8; mf++) {
    int row0 = rowb + mf * 16 + r4;
#pragma unroll
    for (int nf = 0; nf < 4; nf++) {
      int col = colb + nf * 16 + lrow;
#pragma unroll
      for (int r = 0; r < 4; r++) {
        if (PHASE == 2 && z < 2)
          Of[(size_t)(row0 + r) * ldo + col] = acc[mf][nf][r];
        else
          O[(size_t)(row0 + r) * ldo + col] = f2bf(acc[mf][nf][r]);
      }
    }
  }
}

// ---------------- gated activation: out = silu(in[:,0:I]) * in[:,I:2I] ----------------
__global__ __launch_bounds__(256) void act_kernel(
    const unsigned short* __restrict__ in, unsigned short* __restrict__ out,
    int I8, int ldi) {
  int c8 = blockIdx.x * 256 + threadIdx.x;
  if (c8 >= I8) return;
  size_t r = blockIdx.y;
  const unsigned short* p = in + r * (size_t)ldi + (size_t)c8 * 8;
  bf16x8 a = *(const bf16x8*)p;
  bf16x8 g = *(const bf16x8*)(p + (size_t)I8 * 8);
  bf16x8 o;
#pragma unroll
  for (int k = 0; k < 8; k++) {
    float zv = bf2f((unsigned short)a[k]);
    float gv = bf2f((unsigned short)g[k]);
    float v = zv / (1.f + __expf(-zv)) * gv;
    o[k] = (short)f2bf(v);
  }
  *(bf16x8*)(out + r * (size_t)(I8 * 8) + (size_t)c8 * 8) = o;
}

// ---------------- combine: y = ys + sum_k w_k * eo[slot_k] ----------------
__global__ __launch_bounds__(256) void combine_kernel(
    float* __restrict__ y, const float* __restrict__ ysf,
    const unsigned short* __restrict__ eo,
    const int* __restrict__ slot_of, const float* __restrict__ wts) {
  int idx = blockIdx.x * 256 + threadIdx.x;
  int n = idx >> 9;
  int c = (idx & 511) * 4;
  float4 v = *(const float4*)(ysf + (size_t)n * CDIM + c);
#pragma unroll
  for (int k = 0; k < 2; k++) {
    int slot = slot_of[n * 2 + k];
    float w = wts[n * 2 + k];
    ushort4 h = *(const ushort4*)(eo + (size_t)slot * CDIM + c);
    v.x += w * bf2f(h.x);
    v.y += w * bf2f(h.y);
    v.z += w * bf2f(h.z);
    v.w += w * bf2f(h.w);
  }
  *(float4*)(y + (size_t)n * CDIM + c) = v;
}

extern "C" void kernel_launch(void* const* d_in, const int* in_sizes, int n_in,
                              void* d_out, int out_size, void* d_ws, size_t ws_size,
                              hipStream_t stream) {
  const float* x   = (const float*)d_in[0];
  const float* gw  = (const float*)d_in[1];
  const float* w1  = (const float*)d_in[2];
  const float* w2  = (const float*)d_in[3];
  const float* w3  = (const float*)d_in[4];
  const float* sw1 = (const float*)d_in[5];
  const float* sw2 = (const float*)d_in[6];
  const float* sw3 = (const float*)d_in[7];
  float* y = (float*)d_out;

  char* ws = (char*)d_ws;
  size_t off = 0;
  auto alloc = [&](size_t b) -> void* {
    void* p = ws + off;
    off += (b + 255) & ~(size_t)255;
    return p;
  };
  unsigned short* xb    = (unsigned short*)alloc((size_t)N_TOK * CDIM * 2);
  unsigned short* wcat  = (unsigned short*)alloc((size_t)NEXP * ICAT * CDIM * 2);
  unsigned short* w3b   = (unsigned short*)alloc((size_t)NEXP * CDIM * IDIM * 2);
  unsigned short* swcat = (unsigned short*)alloc((size_t)SCAT * CDIM * 2);
  unsigned short* sw3b  = (unsigned short*)alloc((size_t)CDIM * ISDIM * 2);
  unsigned short* hsp   = (unsigned short*)alloc((size_t)N_TOK * SCAT * 2);
  unsigned short* hep   = (unsigned short*)alloc((size_t)NEXP * CAP * ICAT * 2);
  int*   counts  = (int*)alloc(NEXP * 4);
  int*   list    = (int*)alloc((size_t)NEXP * CAP * 4);
  int*   slot_of = (int*)alloc((size_t)N_TOK * 2 * 4);
  float* wtsb    = (float*)alloc((size_t)N_TOK * 2 * 4);
  // aliases (dataflow-safe): hs/he reuse wcat (dead after fc GEMM);
  // ysf reuses hsp, eo reuses hep (dead after act).
  unsigned short* hs = wcat;                               // 4096 x 2816 bf16
  unsigned short* he = wcat + (size_t)N_TOK * ISDIM;       // 8 x 2048 x 1408 bf16
  float*          ysf = (float*)hsp;                       // 4096 x 2048 f32
  unsigned short* eoB = hep;                               // 8 x 2048 x 2048 bf16

  hipMemsetAsync(counts, 0, NEXP * 4, stream);
  routing_kernel<<<N_TOK, 64, 0, stream>>>(x, gw, counts, list, slot_of, wtsb);

  // converts (fp32 -> bf16), concat layouts for w1/w2 and sw1/sw2
  cvt_kernel<<<dim3(8192, 1, 1), 256, 0, stream>>>(x, xb, N_TOK * CDIM, 0, 0);
  cvt_kernel<<<dim3(2816, 1, NEXP), 256, 0, stream>>>(w1, wcat, IDIM * CDIM, 0, (size_t)ICAT * CDIM);
  cvt_kernel<<<dim3(2816, 1, NEXP), 256, 0, stream>>>(w2, wcat, IDIM * CDIM, (size_t)IDIM * CDIM, (size_t)ICAT * CDIM);
  cvt_kernel<<<dim3(22528, 1, 1), 256, 0, stream>>>(w3, w3b, NEXP * CDIM * IDIM, 0, 0);
  cvt_kernel<<<dim3(5632, 1, 1), 256, 0, stream>>>(sw1, swcat, ISDIM * CDIM, 0, 0);
  cvt_kernel<<<dim3(5632, 1, 1), 256, 0, stream>>>(sw2, swcat, ISDIM * CDIM, (size_t)ISDIM * CDIM, 0);
  cvt_kernel<<<dim3(5632, 1, 1), 256, 0, stream>>>(sw3, sw3b, CDIM * ISDIM, 0, 0);

  // fc GEMM: z 0..3 shared (2048x5632 blocks of hsp), z 4..11 experts (gathered)
  moe_gemm<1><<<dim3(88, 1, 12), 512, 0, stream>>>(
      xb, swcat, wcat, hsp, hep, hs, sw3b, he, w3b, ysf, eoB, list, counts);

  // gated activation
  act_kernel<<<dim3(2, N_TOK), 256, 0, stream>>>(hsp, hs, ISDIM / 8, SCAT);
  act_kernel<<<dim3(1, NEXP * CAP), 256, 0, stream>>>(hep, he, IDIM / 8, ICAT);

  // proj GEMM: z 0..1 shared (long K first), z 2..9 experts
  moe_gemm<2><<<dim3(64, 1, 10), 512, 0, stream>>>(
      xb, swcat, wcat, hsp, hep, hs, sw3b, he, w3b, ysf, eoB, list, counts);

  // combine
  combine_kernel<<<(N_TOK * (CDIM / 4)) / 256, 256, 0, stream>>>(y, ysf, eoB, slot_of, wtsb);
}

// Round 6
// 669.178 us; speedup vs baseline: 1.3813x; 1.0252x over previous
//
#include <hip/hip_runtime.h>
#include <stdint.h>

#define N_TOK 4096
#define CDIM  2048
#define NEXP  8
#define IDIM  1408
#define ISDIM 2816
#define CAP   2048
#define ICAT  2816   // [w1;w2] rows per expert
#define SCAT  5632   // [sw1;sw2] rows

typedef __attribute__((ext_vector_type(8))) short bf16x8;
typedef __attribute__((ext_vector_type(4))) float f32x4;

#define GLOAD16(gp, lp) __builtin_amdgcn_global_load_lds( \
    (const __attribute__((address_space(1))) void*)(gp),  \
    (__attribute__((address_space(3))) void*)(lp), 16, 0, 0)

__device__ __forceinline__ unsigned short f2bf(float f) {
  union { float f; unsigned u; } c; c.f = f;
  return (unsigned short)((c.u + 0x7FFFu + ((c.u >> 16) & 1u)) >> 16);
}
__device__ __forceinline__ float bf2f(unsigned short h) {
  union { unsigned u; float f; } c; c.u = (unsigned)h << 16;
  return c.f;
}

__device__ __forceinline__ int xcd_swizzle(int orig, int nwg) {
  int q = nwg >> 3, r = nwg & 7;
  int xcd = orig & 7, idx = orig >> 3;
  return (xcd < r ? xcd * (q + 1) : r * (q + 1) + (xcd - r) * q) + idx;
}

// ---------------- fp32 -> bf16 convert (chunked for concat layouts) ----------------
__global__ __launch_bounds__(256) void cvt_kernel(
    const float* __restrict__ s, unsigned short* __restrict__ d,
    int chunkElems, size_t dstOff, size_t dstStride) {
  size_t z = blockIdx.z;
  size_t i = (size_t)blockIdx.x * 1024 + (size_t)threadIdx.x * 4;
  if (i >= (size_t)chunkElems) return;
  float4 v = *(const float4*)(s + z * chunkElems + i);
  ushort4 o;
  o.x = f2bf(v.x); o.y = f2bf(v.y); o.z = f2bf(v.z); o.w = f2bf(v.w);
  *(ushort4*)(d + z * dstStride + dstOff + i) = o;
}

// ---------------- routing ----------------
__global__ __launch_bounds__(64) void routing_kernel(
    const float* __restrict__ x, const float* __restrict__ gw,
    int* __restrict__ counts, int* __restrict__ list,
    int* __restrict__ slot_of, float* __restrict__ wts) {
  const int n = blockIdx.x;
  const int lane = threadIdx.x;
  const float* xr = x + (size_t)n * CDIM;
  float s[NEXP];
#pragma unroll
  for (int e = 0; e < NEXP; e++) s[e] = 0.f;
  for (int c = lane; c < CDIM; c += 64) {
    float xv = xr[c];
#pragma unroll
    for (int e = 0; e < NEXP; e++) s[e] += xv * gw[e * CDIM + c];
  }
#pragma unroll
  for (int e = 0; e < NEXP; e++) {
    float v = s[e];
    for (int o = 32; o > 0; o >>= 1) v += __shfl_down(v, o);
    s[e] = v;
  }
  if (lane == 0) {
    float mx = s[0];
#pragma unroll
    for (int e = 1; e < NEXP; e++) mx = fmaxf(mx, s[e]);
    float p[NEXP], sum = 0.f;
#pragma unroll
    for (int e = 0; e < NEXP; e++) { p[e] = __expf(s[e] - mx); sum += p[e]; }
    int i0 = 0;
#pragma unroll
    for (int e = 1; e < NEXP; e++) if (p[e] > p[i0]) i0 = e;
    int i1 = (i0 == 0) ? 1 : 0;
#pragma unroll
    for (int e = 0; e < NEXP; e++) if (e != i0 && p[e] > p[i1]) i1 = e;
    float inv = 1.f / sum;
    int s0 = atomicAdd(&counts[i0], 1);
    int s1 = atomicAdd(&counts[i1], 1);
    if (s0 < CAP) list[i0 * CAP + s0] = n; else s0 = 0;
    if (s1 < CAP) list[i1 * CAP + s1] = n; else s1 = 0;
    slot_of[n * 2]     = i0 * CAP + s0;
    slot_of[n * 2 + 1] = i1 * CAP + s1;
    wts[n * 2]     = p[i0] * inv;
    wts[n * 2 + 1] = p[i1] * inv;
  }
}

// ---------------- unified 8-phase deep-pipelined GEMM: Out = A @ B^T ----------------
// 256x256 tile, BK=64 (2 K-halves of 64B/row), 512 threads (8 waves, 2M x 4N).
// LDS [buf][A|B][kkhalf][256 rows x 64B] = 128 KiB; linear gload_lds dest +
// inverse-swizzled global source + XOR-swizzled ds_read (rule #21).
// 4 phases per K-tile, counted vmcnt(8) (never 0 mid-loop), setprio around MFMA.
// K-halves accumulate into the SAME acc quadrants (m225 recipe):
//   P1 kk0/m0 -> acc[0..3], P2 kk0/m1 -> acc[4..7],
//   P3 kk1/m0 -> acc[0..3], P4 kk1/m1 -> acc[4..7].
template <int PHASE>
__global__ __launch_bounds__(512) void moe_gemm(
    const unsigned short* __restrict__ xb,
    const unsigned short* __restrict__ swcat,
    const unsigned short* __restrict__ wcat,
    unsigned short* __restrict__ hsp,
    unsigned short* __restrict__ hep,
    const unsigned short* __restrict__ hs,
    const unsigned short* __restrict__ sw3b,
    const unsigned short* __restrict__ he,
    const unsigned short* __restrict__ w3b,
    float* __restrict__ ysf,
    unsigned short* __restrict__ eo,
    const int* __restrict__ list,
    const int* __restrict__ counts) {
  const int z = blockIdx.z;
  const unsigned short *A, *B;
  unsigned short* O = nullptr;
  float* Of = nullptr;
  int Ka, ldo;
  int cnt = 1 << 30;
  const int* lst = nullptr;
  int Mt, Nt;
  bool gath = false;
  if (PHASE == 1) {
    Mt = 8; Nt = 11; Ka = CDIM;
    if (z < 4) {
      int zm = z >> 1, zn = z & 1;
      A = xb + (size_t)zm * 2048 * CDIM;
      B = swcat + (size_t)zn * ISDIM * CDIM;
      O = hsp + (size_t)zm * 2048 * SCAT + (size_t)zn * ISDIM;
      ldo = SCAT;
    } else {
      int e = z - 4;
      cnt = counts[e]; if (cnt > CAP) cnt = CAP;
      lst = list + e * CAP;
      gath = true;
      A = xb;
      B = wcat + (size_t)e * ICAT * CDIM;
      O = hep + (size_t)e * CAP * ICAT;
      ldo = ICAT;
    }
  } else {
    Mt = 8; Nt = 8;
    if (z < 2) {
      Ka = ISDIM;
      A = hs + (size_t)z * 2048 * ISDIM;
      B = sw3b;
      Of = ysf + (size_t)z * 2048 * CDIM;
      ldo = CDIM;
    } else {
      int e = z - 2;
      cnt = counts[e]; if (cnt > CAP) cnt = CAP;
      Ka = IDIM;
      A = he + (size_t)e * CAP * IDIM;
      B = w3b + (size_t)e * CDIM * IDIM;
      O = eo + (size_t)e * CAP * CDIM;
      ldo = CDIM;
    }
  }
  const int wg = xcd_swizzle(blockIdx.x, Mt * Nt);
  const int mt = wg % Mt, nt = wg / Mt;
  if (mt * 256 >= cnt) return;

  __shared__ __align__(16) char lds[2][2][2][16384]; // [buf][A|B][kk][256x64B]

  const int tid = threadIdx.x;
  // ---- staging: thread covers rows j*128 + (tid>>2), 16B chunk (tid&3)*16
  //      within a 64B K-half row; source col pre-swizzled (inverse of read swz).
  const int srow = tid >> 2;
  const int c16  = (tid & 3) << 4;
  const int scol = c16 ^ (((srow >> 1) & 3) << 4);
  const char* aS[2];
  const char* bS[2];
#pragma unroll
  for (int j = 0; j < 2; j++) {
    int ar = mt * 256 + j * 128 + srow;
    if (PHASE == 1 && gath) ar = (ar < cnt) ? lst[ar] : lst[0];
    aS[j] = (const char*)A + (size_t)ar * Ka * 2 + scol;
    int br = nt * 256 + j * 128 + srow;
    bS[j] = (const char*)B + (size_t)br * Ka * 2 + scol;
  }
  // stage one K-half (h) of K-tile kt into buffer buf: 4 gload_lds
  auto stageHalf = [&](int buf, int kt, int h) {
    size_t kb = (size_t)kt * 128 + (size_t)(h << 6);
    char* aD = &lds[buf][0][h][0] + tid * 16;
    char* bD = &lds[buf][1][h][0] + tid * 16;
    GLOAD16(aS[0] + kb, aD);
    GLOAD16(aS[1] + kb, aD + 8192);
    GLOAD16(bS[0] + kb, bD);
    GLOAD16(bS[1] + kb, bD + 8192);
  };

  const int lane = tid & 63, wid = tid >> 6;
  const int wr = wid >> 2, wc = wid & 3;   // 2 x 4 wave grid, per-wave 128x64
  const int lrow = lane & 15;
  const int klane = (lane >> 4) << 4;      // 0,16,32,48 bytes within 64B half
  const int rsw = ((lrow >> 1) & 3) << 4;
  const int aOff = (wr * 128 + lrow) * 64 + (klane ^ rsw);
  const int bOff = (wc * 64 + lrow) * 64 + (klane ^ rsw);

  f32x4 acc[8][4];
#pragma unroll
  for (int mf = 0; mf < 8; mf++)
#pragma unroll
    for (int nf = 0; nf < 4; nf++) acc[mf][nf] = (f32x4){0.f, 0.f, 0.f, 0.f};

  // prologue: tile0 both halves -> buf0, tile1 kk0 -> buf1 (12 loads)
  stageHalf(0, 0, 0);
  stageHalf(0, 0, 1);
  stageHalf(1, 1, 0);
  asm volatile("s_waitcnt vmcnt(8)" ::: "memory");   // tile0 kk0 resident
  __builtin_amdgcn_s_barrier();

#define MFMA_Q(MB)                                                             \
  _Pragma("unroll")                                                            \
  for (int nf = 0; nf < 4; nf++)                                               \
    _Pragma("unroll")                                                          \
    for (int m = 0; m < 4; m++)                                                \
      acc[(MB) * 4 + m][nf] = __builtin_amdgcn_mfma_f32_16x16x32_bf16(         \
          aR[m], bR[nf], acc[(MB) * 4 + m][nf], 0, 0, 0);

  const int ntk = Ka >> 6;
  for (int t = 0; t < ntk; t++) {
    const int p = t & 1;
    const char* aK0 = &lds[p][0][0][0];
    const char* aK1 = &lds[p][0][1][0];
    const char* bK0 = &lds[p][1][0][0];
    const char* bK1 = &lds[p][1][1][0];
    bf16x8 aR[4], bR[4];
    // ---- P1: kk0, m-half 0 -> acc[0..3]; prefetch (t+1).kk1 -> buf p^1
#pragma unroll
    for (int i = 0; i < 4; i++) aR[i] = *(const bf16x8*)(aK0 + aOff + i * 1024);
#pragma unroll
    for (int i = 0; i < 4; i++) bR[i] = *(const bf16x8*)(bK0 + bOff + i * 1024);
    if (t + 1 < ntk) stageHalf(p ^ 1, t + 1, 1);
    __builtin_amdgcn_s_barrier();
    asm volatile("s_waitcnt lgkmcnt(0)" ::: "memory");
    __builtin_amdgcn_s_setprio(1);
    MFMA_Q(0)
    __builtin_amdgcn_s_setprio(0);
    __builtin_amdgcn_s_barrier();
    // ---- P2: kk0, m-half 1 -> acc[4..7] (reuse bR); vmcnt guards this tile's kk1
#pragma unroll
    for (int i = 0; i < 4; i++) aR[i] = *(const bf16x8*)(aK0 + aOff + (i + 4) * 1024);
    if (t + 1 < ntk) asm volatile("s_waitcnt vmcnt(8)" ::: "memory");
    else             asm volatile("s_waitcnt vmcnt(0)" ::: "memory");
    __builtin_amdgcn_s_barrier();
    asm volatile("s_waitcnt lgkmcnt(0)" ::: "memory");
    __builtin_amdgcn_s_setprio(1);
    MFMA_Q(1)
    __builtin_amdgcn_s_setprio(0);
    __builtin_amdgcn_s_barrier();
    // ---- P3: kk1, m-half 0 -> acc[0..3]; prefetch (t+2).kk0 -> buf p
#pragma unroll
    for (int i = 0; i < 4; i++) aR[i] = *(const bf16x8*)(aK1 + aOff + i * 1024);
#pragma unroll
    for (int i = 0; i < 4; i++) bR[i] = *(const bf16x8*)(bK1 + bOff + i * 1024);
    if (t + 2 < ntk) stageHalf(p, t + 2, 0);
    __builtin_amdgcn_s_barrier();
    asm volatile("s_waitcnt lgkmcnt(0)" ::: "memory");
    __builtin_amdgcn_s_setprio(1);
    MFMA_Q(0)
    __builtin_amdgcn_s_setprio(0);
    __builtin_amdgcn_s_barrier();
    // ---- P4: kk1, m-half 1 -> acc[4..7]; vmcnt guards next tile's kk0
#pragma unroll
    for (int i = 0; i < 4; i++) aR[i] = *(const bf16x8*)(aK1 + aOff + (i + 4) * 1024);
    if (t + 2 < ntk)      asm volatile("s_waitcnt vmcnt(8)" ::: "memory");
    else if (t + 1 < ntk) asm volatile("s_waitcnt vmcnt(4)" ::: "memory");
    __builtin_amdgcn_s_barrier();
    asm volatile("s_waitcnt lgkmcnt(0)" ::: "memory");
    __builtin_amdgcn_s_setprio(1);
    MFMA_Q(1)
    __builtin_amdgcn_s_setprio(0);
    __builtin_amdgcn_s_barrier();
  }
#undef MFMA_Q

  const int rowb = mt * 256 + wr * 128;
  const int colb = nt * 256 + wc * 64;
  const int r4 = (lane >> 4) * 4;
#pragma unroll
  for (int mf = 0; mf < 8; mf++) {
    int row0 = rowb + mf * 16 + r4;
#pragma unroll
    for (int nf = 0; nf < 4; nf++) {
      int col = colb + nf * 16 + lrow;
#pragma unroll
      for (int r = 0; r < 4; r++) {
        if (PHASE == 2 && z < 2)
          Of[(size_t)(row0 + r) * ldo + col] = acc[mf][nf][r];
        else
          O[(size_t)(row0 + r) * ldo + col] = f2bf(acc[mf][nf][r]);
      }
    }
  }
}

// ---------------- gated activation: out = silu(in[:,0:I]) * in[:,I:2I] ----------------
__global__ __launch_bounds__(256) void act_kernel(
    const unsigned short* __restrict__ in, unsigned short* __restrict__ out,
    int I8, int ldi) {
  int c8 = blockIdx.x * 256 + threadIdx.x;
  if (c8 >= I8) return;
  size_t r = blockIdx.y;
  const unsigned short* p = in + r * (size_t)ldi + (size_t)c8 * 8;
  bf16x8 a = *(const bf16x8*)p;
  bf16x8 g = *(const bf16x8*)(p + (size_t)I8 * 8);
  bf16x8 o;
#pragma unroll
  for (int k = 0; k < 8; k++) {
    float zv = bf2f((unsigned short)a[k]);
    float gv = bf2f((unsigned short)g[k]);
    float v = zv / (1.f + __expf(-zv)) * gv;
    o[k] = (short)f2bf(v);
  }
  *(bf16x8*)(out + r * (size_t)(I8 * 8) + (size_t)c8 * 8) = o;
}

// ---------------- combine: y = ys + sum_k w_k * eo[slot_k] ----------------
__global__ __launch_bounds__(256) void combine_kernel(
    float* __restrict__ y, const float* __restrict__ ysf,
    const unsigned short* __restrict__ eo,
    const int* __restrict__ slot_of, const float* __restrict__ wts) {
  int idx = blockIdx.x * 256 + threadIdx.x;
  int n = idx >> 9;
  int c = (idx & 511) * 4;
  float4 v = *(const float4*)(ysf + (size_t)n * CDIM + c);
#pragma unroll
  for (int k = 0; k < 2; k++) {
    int slot = slot_of[n * 2 + k];
    float w = wts[n * 2 + k];
    ushort4 h = *(const ushort4*)(eo + (size_t)slot * CDIM + c);
    v.x += w * bf2f(h.x);
    v.y += w * bf2f(h.y);
    v.z += w * bf2f(h.z);
    v.w += w * bf2f(h.w);
  }
  *(float4*)(y + (size_t)n * CDIM + c) = v;
}

extern "C" void kernel_launch(void* const* d_in, const int* in_sizes, int n_in,
                              void* d_out, int out_size, void* d_ws, size_t ws_size,
                              hipStream_t stream) {
  const float* x   = (const float*)d_in[0];
  const float* gw  = (const float*)d_in[1];
  const float* w1  = (const float*)d_in[2];
  const float* w2  = (const float*)d_in[3];
  const float* w3  = (const float*)d_in[4];
  const float* sw1 = (const float*)d_in[5];
  const float* sw2 = (const float*)d_in[6];
  const float* sw3 = (const float*)d_in[7];
  float* y = (float*)d_out;

  char* ws = (char*)d_ws;
  size_t off = 0;
  auto alloc = [&](size_t b) -> void* {
    void* p = ws + off;
    off += (b + 255) & ~(size_t)255;
    return p;
  };
  unsigned short* xb    = (unsigned short*)alloc((size_t)N_TOK * CDIM * 2);
  unsigned short* wcat  = (unsigned short*)alloc((size_t)NEXP * ICAT * CDIM * 2);
  unsigned short* w3b   = (unsigned short*)alloc((size_t)NEXP * CDIM * IDIM * 2);
  unsigned short* swcat = (unsigned short*)alloc((size_t)SCAT * CDIM * 2);
  unsigned short* sw3b  = (unsigned short*)alloc((size_t)CDIM * ISDIM * 2);
  unsigned short* hsp   = (unsigned short*)alloc((size_t)N_TOK * SCAT * 2);
  unsigned short* hep   = (unsigned short*)alloc((size_t)NEXP * CAP * ICAT * 2);
  int*   counts  = (int*)alloc(NEXP * 4);
  int*   list    = (int*)alloc((size_t)NEXP * CAP * 4);
  int*   slot_of = (int*)alloc((size_t)N_TOK * 2 * 4);
  float* wtsb    = (float*)alloc((size_t)N_TOK * 2 * 4);
  // aliases (dataflow-safe): hs/he reuse wcat (dead after fc GEMM);
  // ysf reuses hsp, eo reuses hep (dead after act).
  unsigned short* hs = wcat;                               // 4096 x 2816 bf16
  unsigned short* he = wcat + (size_t)N_TOK * ISDIM;       // 8 x 2048 x 1408 bf16
  float*          ysf = (float*)hsp;                       // 4096 x 2048 f32
  unsigned short* eoB = hep;                               // 8 x 2048 x 2048 bf16

  hipMemsetAsync(counts, 0, NEXP * 4, stream);
  routing_kernel<<<N_TOK, 64, 0, stream>>>(x, gw, counts, list, slot_of, wtsb);

  // converts (fp32 -> bf16), concat layouts for w1/w2 and sw1/sw2
  cvt_kernel<<<dim3(8192, 1, 1), 256, 0, stream>>>(x, xb, N_TOK * CDIM, 0, 0);
  cvt_kernel<<<dim3(2816, 1, NEXP), 256, 0, stream>>>(w1, wcat, IDIM * CDIM, 0, (size_t)ICAT * CDIM);
  cvt_kernel<<<dim3(2816, 1, NEXP), 256, 0, stream>>>(w2, wcat, IDIM * CDIM, (size_t)IDIM * CDIM, (size_t)ICAT * CDIM);
  cvt_kernel<<<dim3(22528, 1, 1), 256, 0, stream>>>(w3, w3b, NEXP * CDIM * IDIM, 0, 0);
  cvt_kernel<<<dim3(5632, 1, 1), 256, 0, stream>>>(sw1, swcat, ISDIM * CDIM, 0, 0);
  cvt_kernel<<<dim3(5632, 1, 1), 256, 0, stream>>>(sw2, swcat, ISDIM * CDIM, (size_t)ISDIM * CDIM, 0);
  cvt_kernel<<<dim3(5632, 1, 1), 256, 0, stream>>>(sw3, sw3b, CDIM * ISDIM, 0, 0);

  // fc GEMM: z 0..3 shared (2048x5632 blocks of hsp), z 4..11 experts (gathered)
  moe_gemm<1><<<dim3(88, 1, 12), 512, 0, stream>>>(
      xb, swcat, wcat, hsp, hep, hs, sw3b, he, w3b, ysf, eoB, list, counts);

  // gated activation
  act_kernel<<<dim3(2, N_TOK), 256, 0, stream>>>(hsp, hs, ISDIM / 8, SCAT);
  act_kernel<<<dim3(1, NEXP * CAP), 256, 0, stream>>>(hep, he, IDIM / 8, ICAT);

  // proj GEMM: z 0..1 shared (long K first), z 2..9 experts
  moe_gemm<2><<<dim3(64, 1, 10), 512, 0, stream>>>(
      xb, swcat, wcat, hsp, hep, hs, sw3b, he, w3b, ysf, eoB, list, counts);

  // combine
  combine_kernel<<<(N_TOK * (CDIM / 4)) / 256, 256, 0, stream>>>(y, ysf, eoB, slot_of, wtsb);
}

// Round 7
// 631.293 us; speedup vs baseline: 1.4642x; 1.0600x over previous
//
#include <hip/hip_runtime.h>
#include <stdint.h>

#define N_TOK 4096
#define CDIM  2048
#define NEXP  8
#define IDIM  1408
#define ISDIM 2816
#define CAP   2048
#define ICAT  2816   // interleaved [w1;w2] rows per expert (128-row groups)
#define SCAT  5632   // interleaved [sw1;sw2] rows (2 col-half sections)

typedef __attribute__((ext_vector_type(8))) short bf16x8;
typedef __attribute__((ext_vector_type(4))) float f32x4;

#define GLOAD16(gp, lp) __builtin_amdgcn_global_load_lds( \
    (const __attribute__((address_space(1))) void*)(gp),  \
    (__attribute__((address_space(3))) void*)(lp), 16, 0, 0)

__device__ __forceinline__ unsigned short f2bf(float f) {
  union { float f; unsigned u; } c; c.f = f;
  return (unsigned short)((c.u + 0x7FFFu + ((c.u >> 16) & 1u)) >> 16);
}
__device__ __forceinline__ float bf2f(unsigned short h) {
  union { unsigned u; float f; } c; c.u = (unsigned)h << 16;
  return c.f;
}

__device__ __forceinline__ int xcd_swizzle(int orig, int nwg) {
  int q = nwg >> 3, r = nwg & 7;
  int xcd = orig & 7, idx = orig >> 3;
  return (xcd < r ? xcd * (q + 1) : r * (q + 1) + (xcd - r) * q) + idx;
}

// ---------------- single fused fp32 -> bf16 convert, all tensors ----------------
// 2048 elems per block (8/thread). Segments:
//   [0,4096)            x        flat
//   [4096,15360)        w3       flat
//   [15360,18176)       sw3      flat
//   [18176,40704)       w1/w2    row-interleaved into wcat (128-row groups)
//   [40704,46336)       sw1/sw2  row-interleaved into swcat (2 zn sections)
__global__ __launch_bounds__(256) void cvt_all(
    const float* __restrict__ x, const float* __restrict__ w1,
    const float* __restrict__ w2, const float* __restrict__ w3,
    const float* __restrict__ sw1, const float* __restrict__ sw2,
    const float* __restrict__ sw3,
    unsigned short* __restrict__ xb, unsigned short* __restrict__ wcat,
    unsigned short* __restrict__ w3b, unsigned short* __restrict__ swcat,
    unsigned short* __restrict__ sw3b) {
  const int b = blockIdx.x;
  const int t = threadIdx.x;
  const float* src;
  unsigned short* dst;
  if (b < 4096) {
    src = x + (size_t)b * 2048;  dst = xb + (size_t)b * 2048;
  } else if (b < 15360) {
    size_t o = (size_t)(b - 4096) * 2048;  src = w3 + o;  dst = w3b + o;
  } else if (b < 18176) {
    size_t o = (size_t)(b - 15360) * 2048; src = sw3 + o; dst = sw3b + o;
  } else if (b < 40704) {
    int g = b - 18176;
    int e = g / 2816, r = g - e * 2816;
    int dr;
    if (r < 1408) { src = w1 + ((size_t)e * 1408 + r) * 2048; dr = (r >> 7) * 256 + (r & 127); }
    else { int r2 = r - 1408; src = w2 + ((size_t)e * 1408 + r2) * 2048; dr = (r2 >> 7) * 256 + 128 + (r2 & 127); }
    dst = wcat + ((size_t)e * ICAT + dr) * 2048;
  } else {
    int g = b - 40704;
    int dr;
    if (g < 2816) {
      int zn = g >= 1408, rr = g - zn * 1408;
      src = sw1 + (size_t)g * 2048;
      dr = zn * 2816 + (rr >> 7) * 256 + (rr & 127);
    } else {
      int r = g - 2816;
      int zn = r >= 1408, rr = r - zn * 1408;
      src = sw2 + (size_t)r * 2048;
      dr = zn * 2816 + (rr >> 7) * 256 + 128 + (rr & 127);
    }
    dst = swcat + (size_t)dr * 2048;
  }
  size_t i = (size_t)t * 8;
  float4 v0 = *(const float4*)(src + i);
  float4 v1 = *(const float4*)(src + i + 4);
  bf16x8 o;
  o[0] = (short)f2bf(v0.x); o[1] = (short)f2bf(v0.y);
  o[2] = (short)f2bf(v0.z); o[3] = (short)f2bf(v0.w);
  o[4] = (short)f2bf(v1.x); o[5] = (short)f2bf(v1.y);
  o[6] = (short)f2bf(v1.z); o[7] = (short)f2bf(v1.w);
  *(bf16x8*)(dst + i) = o;
}

// ---------------- routing ----------------
__global__ __launch_bounds__(64) void routing_kernel(
    const float* __restrict__ x, const float* __restrict__ gw,
    int* __restrict__ counts, int* __restrict__ list,
    int* __restrict__ slot_of, float* __restrict__ wts) {
  const int n = blockIdx.x;
  const int lane = threadIdx.x;
  const float* xr = x + (size_t)n * CDIM;
  float s[NEXP];
#pragma unroll
  for (int e = 0; e < NEXP; e++) s[e] = 0.f;
  for (int c = lane; c < CDIM; c += 64) {
    float xv = xr[c];
#pragma unroll
    for (int e = 0; e < NEXP; e++) s[e] += xv * gw[e * CDIM + c];
  }
#pragma unroll
  for (int e = 0; e < NEXP; e++) {
    float v = s[e];
    for (int o = 32; o > 0; o >>= 1) v += __shfl_down(v, o);
    s[e] = v;
  }
  if (lane == 0) {
    float mx = s[0];
#pragma unroll
    for (int e = 1; e < NEXP; e++) mx = fmaxf(mx, s[e]);
    float p[NEXP], sum = 0.f;
#pragma unroll
    for (int e = 0; e < NEXP; e++) { p[e] = __expf(s[e] - mx); sum += p[e]; }
    int i0 = 0;
#pragma unroll
    for (int e = 1; e < NEXP; e++) if (p[e] > p[i0]) i0 = e;
    int i1 = (i0 == 0) ? 1 : 0;
#pragma unroll
    for (int e = 0; e < NEXP; e++) if (e != i0 && p[e] > p[i1]) i1 = e;
    float inv = 1.f / sum;
    int s0 = atomicAdd(&counts[i0], 1);
    int s1 = atomicAdd(&counts[i1], 1);
    if (s0 < CAP) list[i0 * CAP + s0] = n; else s0 = 0;
    if (s1 < CAP) list[i1 * CAP + s1] = n; else s1 = 0;
    slot_of[n * 2]     = i0 * CAP + s0;
    slot_of[n * 2 + 1] = i1 * CAP + s1;
    wts[n * 2]     = p[i0] * inv;
    wts[n * 2 + 1] = p[i1] * inv;
  }
}

// ---------------- unified 8-phase deep-pipelined GEMM: Out = A @ B^T ----------------
// 256x256 tile, BK=64 (2 K-halves of 64B/row), 512 threads (8 waves, 2M x 4N).
// Verified R6 core: counted vmcnt(8), dual barriers/phase, T2 both-sides swizzle,
// m225 accumulator recipe (kk-halves accumulate into the SAME acc quadrants).
// PHASE 1 (fc): B rows are [h1;h2] interleaved in 128-row groups -> block computes
//   h1 (local cols 0-127) and h2 (128-255) for the SAME features; fused epilogue
//   computes silu(h1)*h2 via an LDS h2 exchange, writing a 256x128 bf16 tile.
//   z<4: shared quadrants -> hs.  z>=4: expert e=z-4 gathered -> he[e].
// PHASE 2 (proj): z<2 shared halves (hs @ sw3^T -> ysf fp32); z>=2 expert -> eo.
template <int PHASE>
__global__ __launch_bounds__(512) void moe_gemm(
    const unsigned short* __restrict__ xb,
    const unsigned short* __restrict__ swcat,
    const unsigned short* __restrict__ wcat,
    unsigned short* __restrict__ hs_out,
    unsigned short* __restrict__ he_out,
    const unsigned short* __restrict__ hs,
    const unsigned short* __restrict__ sw3b,
    const unsigned short* __restrict__ he,
    const unsigned short* __restrict__ w3b,
    float* __restrict__ ysf,
    unsigned short* __restrict__ eo,
    const int* __restrict__ list,
    const int* __restrict__ counts) {
  const int z = blockIdx.z;
  const unsigned short *A, *B;
  unsigned short* O = nullptr;
  float* Of = nullptr;
  int Ka, ldo;
  int cnt = 1 << 30;
  const int* lst = nullptr;
  int Mt, Nt;
  bool gath = false;
  if (PHASE == 1) {
    Mt = 8; Nt = 11; Ka = CDIM;
    if (z < 4) {
      int zm = z >> 1, zn = z & 1;
      A = xb + (size_t)zm * 2048 * CDIM;
      B = swcat + (size_t)zn * 2816 * CDIM;
      O = hs_out + (size_t)zm * 2048 * ISDIM + (size_t)zn * 1408;
      ldo = ISDIM;
    } else {
      int e = z - 4;
      cnt = counts[e]; if (cnt > CAP) cnt = CAP;
      lst = list + e * CAP;
      gath = true;
      A = xb;
      B = wcat + (size_t)e * ICAT * CDIM;
      O = he_out + (size_t)e * CAP * IDIM;
      ldo = IDIM;
    }
  } else {
    Mt = 8; Nt = 8;
    if (z < 2) {
      Ka = ISDIM;
      A = hs + (size_t)z * 2048 * ISDIM;
      B = sw3b;
      Of = ysf + (size_t)z * 2048 * CDIM;
      ldo = CDIM;
    } else {
      int e = z - 2;
      cnt = counts[e]; if (cnt > CAP) cnt = CAP;
      Ka = IDIM;
      A = he + (size_t)e * CAP * IDIM;
      B = w3b + (size_t)e * CDIM * IDIM;
      O = eo + (size_t)e * CAP * CDIM;
      ldo = CDIM;
    }
  }
  const int wg = xcd_swizzle(blockIdx.x, Mt * Nt);
  const int mt = wg % Mt, nt = wg / Mt;
  if (mt * 256 >= cnt) return;

  __shared__ __align__(16) char lds[2][2][2][16384]; // [buf][A|B][kk][256x64B]

  const int tid = threadIdx.x;
  const int srow = tid >> 2;
  const int c16  = (tid & 3) << 4;
  const int scol = c16 ^ (((srow >> 1) & 3) << 4);
  const char* aS[2];
  const char* bS[2];
#pragma unroll
  for (int j = 0; j < 2; j++) {
    int ar = mt * 256 + j * 128 + srow;
    if (PHASE == 1 && gath) ar = (ar < cnt) ? lst[ar] : lst[0];
    aS[j] = (const char*)A + (size_t)ar * Ka * 2 + scol;
    int br = nt * 256 + j * 128 + srow;
    bS[j] = (const char*)B + (size_t)br * Ka * 2 + scol;
  }
  auto stageHalf = [&](int buf, int kt, int h) {
    size_t kb = (size_t)kt * 128 + (size_t)(h << 6);
    char* aD = &lds[buf][0][h][0] + tid * 16;
    char* bD = &lds[buf][1][h][0] + tid * 16;
    GLOAD16(aS[0] + kb, aD);
    GLOAD16(aS[1] + kb, aD + 8192);
    GLOAD16(bS[0] + kb, bD);
    GLOAD16(bS[1] + kb, bD + 8192);
  };

  const int lane = tid & 63, wid = tid >> 6;
  const int wr = wid >> 2, wc = wid & 3;   // 2 x 4 wave grid, per-wave 128x64
  const int lrow = lane & 15;
  const int klane = (lane >> 4) << 4;
  const int rsw = ((lrow >> 1) & 3) << 4;
  const int aOff = (wr * 128 + lrow) * 64 + (klane ^ rsw);
  const int bOff = (wc * 64 + lrow) * 64 + (klane ^ rsw);

  f32x4 acc[8][4];
#pragma unroll
  for (int mf = 0; mf < 8; mf++)
#pragma unroll
    for (int nf = 0; nf < 4; nf++) acc[mf][nf] = (f32x4){0.f, 0.f, 0.f, 0.f};

  stageHalf(0, 0, 0);
  stageHalf(0, 0, 1);
  stageHalf(1, 1, 0);
  asm volatile("s_waitcnt vmcnt(8)" ::: "memory");
  __builtin_amdgcn_s_barrier();

#define MFMA_Q(MB)                                                             \
  _Pragma("unroll")                                                            \
  for (int nf = 0; nf < 4; nf++)                                               \
    _Pragma("unroll")                                                          \
    for (int m = 0; m < 4; m++)                                                \
      acc[(MB) * 4 + m][nf] = __builtin_amdgcn_mfma_f32_16x16x32_bf16(         \
          aR[m], bR[nf], acc[(MB) * 4 + m][nf], 0, 0, 0);

  const int ntk = Ka >> 6;
  for (int t = 0; t < ntk; t++) {
    const int p = t & 1;
    const char* aK0 = &lds[p][0][0][0];
    const char* aK1 = &lds[p][0][1][0];
    const char* bK0 = &lds[p][1][0][0];
    const char* bK1 = &lds[p][1][1][0];
    bf16x8 aR[4], bR[4];
    // ---- P1: kk0, m-half 0 -> acc[0..3]; prefetch (t+1).kk1 -> buf p^1
#pragma unroll
    for (int i = 0; i < 4; i++) aR[i] = *(const bf16x8*)(aK0 + aOff + i * 1024);
#pragma unroll
    for (int i = 0; i < 4; i++) bR[i] = *(const bf16x8*)(bK0 + bOff + i * 1024);
    if (t + 1 < ntk) stageHalf(p ^ 1, t + 1, 1);
    __builtin_amdgcn_s_barrier();
    asm volatile("s_waitcnt lgkmcnt(0)" ::: "memory");
    __builtin_amdgcn_s_setprio(1);
    MFMA_Q(0)
    __builtin_amdgcn_s_setprio(0);
    __builtin_amdgcn_s_barrier();
    // ---- P2: kk0, m-half 1 -> acc[4..7]; vmcnt guards this tile's kk1
#pragma unroll
    for (int i = 0; i < 4; i++) aR[i] = *(const bf16x8*)(aK0 + aOff + (i + 4) * 1024);
    if (t + 1 < ntk) asm volatile("s_waitcnt vmcnt(8)" ::: "memory");
    else             asm volatile("s_waitcnt vmcnt(0)" ::: "memory");
    __builtin_amdgcn_s_barrier();
    asm volatile("s_waitcnt lgkmcnt(0)" ::: "memory");
    __builtin_amdgcn_s_setprio(1);
    MFMA_Q(1)
    __builtin_amdgcn_s_setprio(0);
    __builtin_amdgcn_s_barrier();
    // ---- P3: kk1, m-half 0 -> acc[0..3]; prefetch (t+2).kk0 -> buf p
#pragma unroll
    for (int i = 0; i < 4; i++) aR[i] = *(const bf16x8*)(aK1 + aOff + i * 1024);
#pragma unroll
    for (int i = 0; i < 4; i++) bR[i] = *(const bf16x8*)(bK1 + bOff + i * 1024);
    if (t + 2 < ntk) stageHalf(p, t + 2, 0);
    __builtin_amdgcn_s_barrier();
    asm volatile("s_waitcnt lgkmcnt(0)" ::: "memory");
    __builtin_amdgcn_s_setprio(1);
    MFMA_Q(0)
    __builtin_amdgcn_s_setprio(0);
    __builtin_amdgcn_s_barrier();
    // ---- P4: kk1, m-half 1 -> acc[4..7]; vmcnt guards next tile's kk0
#pragma unroll
    for (int i = 0; i < 4; i++) aR[i] = *(const bf16x8*)(aK1 + aOff + (i + 4) * 1024);
    if (t + 2 < ntk)      asm volatile("s_waitcnt vmcnt(8)" ::: "memory");
    else if (t + 1 < ntk) asm volatile("s_waitcnt vmcnt(4)" ::: "memory");
    __builtin_amdgcn_s_barrier();
    asm volatile("s_waitcnt lgkmcnt(0)" ::: "memory");
    __builtin_amdgcn_s_setprio(1);
    MFMA_Q(1)
    __builtin_amdgcn_s_setprio(0);
    __builtin_amdgcn_s_barrier();
  }
#undef MFMA_Q

  const int r4 = (lane >> 4) * 4;
  if (PHASE == 1) {
    // fused gate: waves wc>=2 publish h2 (f32) via LDS, waves wc<2 combine.
    float* ldsF = (float*)&lds[0][0][0][0];      // 256 x 128 f32 = 128 KiB
    const int rbase = wr * 128 + r4;
    if (wc >= 2) {
      const int cb = (wc - 2) * 64;
#pragma unroll
      for (int mf = 0; mf < 8; mf++)
#pragma unroll
        for (int nf = 0; nf < 4; nf++) {
          int cc = cb + nf * 16 + lrow;
#pragma unroll
          for (int r = 0; r < 4; r++)
            ldsF[(rbase + mf * 16 + r) * 128 + cc] = acc[mf][nf][r];
        }
    }
    __syncthreads();
    if (wc < 2) {
      const int cb = wc * 64;
#pragma unroll
      for (int mf = 0; mf < 8; mf++) {
        int row0 = mt * 256 + wr * 128 + mf * 16 + r4;
#pragma unroll
        for (int nf = 0; nf < 4; nf++) {
          int cc = cb + nf * 16 + lrow;
          int col = nt * 128 + cc;
#pragma unroll
          for (int r = 0; r < 4; r++) {
            float z1 = acc[mf][nf][r];
            float z2 = ldsF[(rbase + mf * 16 + r) * 128 + cc];
            float gv = z1 / (1.f + __expf(-z1)) * z2;
            O[(size_t)(row0 + r) * ldo + col] = f2bf(gv);
          }
        }
      }
    }
  } else {
    const int rowb = mt * 256 + wr * 128;
    const int colb = nt * 256 + wc * 64;
#pragma unroll
    for (int mf = 0; mf < 8; mf++) {
      int row0 = rowb + mf * 16 + r4;
#pragma unroll
      for (int nf = 0; nf < 4; nf++) {
        int col = colb + nf * 16 + lrow;
#pragma unroll
        for (int r = 0; r < 4; r++) {
          if (z < 2)
            Of[(size_t)(row0 + r) * ldo + col] = acc[mf][nf][r];
          else
            O[(size_t)(row0 + r) * ldo + col] = f2bf(acc[mf][nf][r]);
        }
      }
    }
  }
}

// ---------------- combine: y = ys + sum_k w_k * eo[slot_k] ----------------
__global__ __launch_bounds__(256) void combine_kernel(
    float* __restrict__ y, const float* __restrict__ ysf,
    const unsigned short* __restrict__ eo,
    const int* __restrict__ slot_of, const float* __restrict__ wts) {
  int idx = blockIdx.x * 256 + threadIdx.x;
  int n = idx >> 9;
  int c = (idx & 511) * 4;
  float4 v = *(const float4*)(ysf + (size_t)n * CDIM + c);
#pragma unroll
  for (int k = 0; k < 2; k++) {
    int slot = slot_of[n * 2 + k];
    float w = wts[n * 2 + k];
    ushort4 h = *(const ushort4*)(eo + (size_t)slot * CDIM + c);
    v.x += w * bf2f(h.x);
    v.y += w * bf2f(h.y);
    v.z += w * bf2f(h.z);
    v.w += w * bf2f(h.w);
  }
  *(float4*)(y + (size_t)n * CDIM + c) = v;
}

extern "C" void kernel_launch(void* const* d_in, const int* in_sizes, int n_in,
                              void* d_out, int out_size, void* d_ws, size_t ws_size,
                              hipStream_t stream) {
  const float* x   = (const float*)d_in[0];
  const float* gw  = (const float*)d_in[1];
  const float* w1  = (const float*)d_in[2];
  const float* w2  = (const float*)d_in[3];
  const float* w3  = (const float*)d_in[4];
  const float* sw1 = (const float*)d_in[5];
  const float* sw2 = (const float*)d_in[6];
  const float* sw3 = (const float*)d_in[7];
  float* y = (float*)d_out;

  char* ws = (char*)d_ws;
  size_t off = 0;
  auto alloc = [&](size_t b) -> void* {
    void* p = ws + off;
    off += (b + 255) & ~(size_t)255;
    return p;
  };
  unsigned short* xb    = (unsigned short*)alloc((size_t)N_TOK * CDIM * 2);
  unsigned short* wcat  = (unsigned short*)alloc((size_t)NEXP * ICAT * CDIM * 2);
  unsigned short* w3b   = (unsigned short*)alloc((size_t)NEXP * CDIM * IDIM * 2);
  unsigned short* swcat = (unsigned short*)alloc((size_t)SCAT * CDIM * 2);
  unsigned short* sw3b  = (unsigned short*)alloc((size_t)CDIM * ISDIM * 2);
  unsigned short* hs    = (unsigned short*)alloc((size_t)N_TOK * ISDIM * 2);
  unsigned short* he    = (unsigned short*)alloc((size_t)NEXP * CAP * IDIM * 2);
  float*          ysf   = (float*)alloc((size_t)N_TOK * CDIM * 4);
  int*   counts  = (int*)alloc(NEXP * 4);
  int*   list    = (int*)alloc((size_t)NEXP * CAP * 4);
  int*   slot_of = (int*)alloc((size_t)N_TOK * 2 * 4);
  float* wtsb    = (float*)alloc((size_t)N_TOK * 2 * 4);
  // alias: eo reuses wcat (dead after fc GEMM); 67.1MB <= 92.3MB.
  unsigned short* eoB = wcat;

  hipMemsetAsync(counts, 0, NEXP * 4, stream);
  routing_kernel<<<N_TOK, 64, 0, stream>>>(x, gw, counts, list, slot_of, wtsb);

  // one fused convert for all tensors (incl. w1/w2 & sw1/sw2 row interleave)
  cvt_all<<<46336, 256, 0, stream>>>(x, w1, w2, w3, sw1, sw2, sw3,
                                     xb, wcat, w3b, swcat, sw3b);

  // fc GEMM with fused silu-gate epilogue:
  //   z 0..3 shared -> hs [4096 x 2816]; z 4..11 experts (gathered) -> he
  moe_gemm<1><<<dim3(88, 1, 12), 512, 0, stream>>>(
      xb, swcat, wcat, hs, he, hs, sw3b, he, w3b, ysf, eoB, list, counts);

  // proj GEMM: z 0..1 shared (long K first), z 2..9 experts
  moe_gemm<2><<<dim3(64, 1, 10), 512, 0, stream>>>(
      xb, swcat, wcat, hs, he, hs, sw3b, he, w3b, ysf, eoB, list, counts);

  // combine
  combine_kernel<<<(N_TOK * (CDIM / 4)) / 256, 256, 0, stream>>>(y, ysf, eoB, slot_of, wtsb);
}

// Round 8
// 591.760 us; speedup vs baseline: 1.5620x; 1.0668x over previous
//
#include <hip/hip_runtime.h>
#include <stdint.h>

#define N_TOK 4096
#define CDIM  2048
#define NEXP  8
#define IDIM  1408
#define ISDIM 2816
#define CAP   2048
#define ICAT  2816   // interleaved [w1;w2] rows per expert (128-row groups)
#define SCAT  5632   // interleaved [sw1;sw2] rows (2 col-half sections)

typedef __attribute__((ext_vector_type(8))) short bf16x8;
typedef __attribute__((ext_vector_type(4))) float f32x4;

#define GLOAD16(gp, lp) __builtin_amdgcn_global_load_lds( \
    (const __attribute__((address_space(1))) void*)(gp),  \
    (__attribute__((address_space(3))) void*)(lp), 16, 0, 0)

__device__ __forceinline__ unsigned short f2bf(float f) {
  union { float f; unsigned u; } c; c.f = f;
  return (unsigned short)((c.u + 0x7FFFu + ((c.u >> 16) & 1u)) >> 16);
}
__device__ __forceinline__ float bf2f(unsigned short h) {
  union { unsigned u; float f; } c; c.u = (unsigned)h << 16;
  return c.f;
}

__device__ __forceinline__ int xcd_swizzle(int orig, int nwg) {
  int q = nwg >> 3, r = nwg & 7;
  int xcd = orig & 7, idx = orig >> 3;
  return (xcd < r ? xcd * (q + 1) : r * (q + 1) + (xcd - r) * q) + idx;
}

// ---------------- single fused fp32 -> bf16 convert, all tensors ----------------
__global__ __launch_bounds__(256) void cvt_all(
    const float* __restrict__ x, const float* __restrict__ w1,
    const float* __restrict__ w2, const float* __restrict__ w3,
    const float* __restrict__ sw1, const float* __restrict__ sw2,
    const float* __restrict__ sw3,
    unsigned short* __restrict__ xb, unsigned short* __restrict__ wcat,
    unsigned short* __restrict__ w3b, unsigned short* __restrict__ swcat,
    unsigned short* __restrict__ sw3b) {
  const int b = blockIdx.x;
  const int t = threadIdx.x;
  const float* src;
  unsigned short* dst;
  if (b < 4096) {
    src = x + (size_t)b * 2048;  dst = xb + (size_t)b * 2048;
  } else if (b < 15360) {
    size_t o = (size_t)(b - 4096) * 2048;  src = w3 + o;  dst = w3b + o;
  } else if (b < 18176) {
    size_t o = (size_t)(b - 15360) * 2048; src = sw3 + o; dst = sw3b + o;
  } else if (b < 40704) {
    int g = b - 18176;
    int e = g / 2816, r = g - e * 2816;
    int dr;
    if (r < 1408) { src = w1 + ((size_t)e * 1408 + r) * 2048; dr = (r >> 7) * 256 + (r & 127); }
    else { int r2 = r - 1408; src = w2 + ((size_t)e * 1408 + r2) * 2048; dr = (r2 >> 7) * 256 + 128 + (r2 & 127); }
    dst = wcat + ((size_t)e * ICAT + dr) * 2048;
  } else {
    int g = b - 40704;
    int dr;
    if (g < 2816) {
      int zn = g >= 1408, rr = g - zn * 1408;
      src = sw1 + (size_t)g * 2048;
      dr = zn * 2816 + (rr >> 7) * 256 + (rr & 127);
    } else {
      int r = g - 2816;
      int zn = r >= 1408, rr = r - zn * 1408;
      src = sw2 + (size_t)r * 2048;
      dr = zn * 2816 + (rr >> 7) * 256 + 128 + (rr & 127);
    }
    dst = swcat + (size_t)dr * 2048;
  }
  size_t i = (size_t)t * 8;
  float4 v0 = *(const float4*)(src + i);
  float4 v1 = *(const float4*)(src + i + 4);
  bf16x8 o;
  o[0] = (short)f2bf(v0.x); o[1] = (short)f2bf(v0.y);
  o[2] = (short)f2bf(v0.z); o[3] = (short)f2bf(v0.w);
  o[4] = (short)f2bf(v1.x); o[5] = (short)f2bf(v1.y);
  o[6] = (short)f2bf(v1.z); o[7] = (short)f2bf(v1.w);
  *(bf16x8*)(dst + i) = o;
}

// ---------------- routing ----------------
__global__ __launch_bounds__(64) void routing_kernel(
    const float* __restrict__ x, const float* __restrict__ gw,
    int* __restrict__ counts, int* __restrict__ list,
    int* __restrict__ slot_of, float* __restrict__ wts) {
  const int n = blockIdx.x;
  const int lane = threadIdx.x;
  const float* xr = x + (size_t)n * CDIM;
  float s[NEXP];
#pragma unroll
  for (int e = 0; e < NEXP; e++) s[e] = 0.f;
  for (int c = lane; c < CDIM; c += 64) {
    float xv = xr[c];
#pragma unroll
    for (int e = 0; e < NEXP; e++) s[e] += xv * gw[e * CDIM + c];
  }
#pragma unroll
  for (int e = 0; e < NEXP; e++) {
    float v = s[e];
    for (int o = 32; o > 0; o >>= 1) v += __shfl_down(v, o);
    s[e] = v;
  }
  if (lane == 0) {
    float mx = s[0];
#pragma unroll
    for (int e = 1; e < NEXP; e++) mx = fmaxf(mx, s[e]);
    float p[NEXP], sum = 0.f;
#pragma unroll
    for (int e = 0; e < NEXP; e++) { p[e] = __expf(s[e] - mx); sum += p[e]; }
    int i0 = 0;
#pragma unroll
    for (int e = 1; e < NEXP; e++) if (p[e] > p[i0]) i0 = e;
    int i1 = (i0 == 0) ? 1 : 0;
#pragma unroll
    for (int e = 0; e < NEXP; e++) if (e != i0 && p[e] > p[i1]) i1 = e;
    float inv = 1.f / sum;
    int s0 = atomicAdd(&counts[i0], 1);
    int s1 = atomicAdd(&counts[i1], 1);
    if (s0 < CAP) list[i0 * CAP + s0] = n; else s0 = 0;
    if (s1 < CAP) list[i1 * CAP + s1] = n; else s1 = 0;
    slot_of[n * 2]     = i0 * CAP + s0;
    slot_of[n * 2 + 1] = i1 * CAP + s1;
    wts[n * 2]     = p[i0] * inv;
    wts[n * 2 + 1] = p[i1] * inv;
  }
}

// ---------------- unified 8-phase deep-pipelined GEMM: Out = A @ B^T ----------------
// 256x256 tile, BK=64 (2 K-halves of 64B/row), 512 threads (8 waves, 2M x 4N).
// R8: 2 gloads per phase (stageA/stageB split), ledger-exact vmcnt(8)/(4)/(0);
// epilogue h2-exchange XOR-swizzled (conflict-free).
template <int PHASE>
__global__ __launch_bounds__(512) void moe_gemm(
    const unsigned short* __restrict__ xb,
    const unsigned short* __restrict__ swcat,
    const unsigned short* __restrict__ wcat,
    unsigned short* __restrict__ hs_out,
    unsigned short* __restrict__ he_out,
    const unsigned short* __restrict__ hs,
    const unsigned short* __restrict__ sw3b,
    const unsigned short* __restrict__ he,
    const unsigned short* __restrict__ w3b,
    float* __restrict__ ysf,
    unsigned short* __restrict__ eo,
    const int* __restrict__ list,
    const int* __restrict__ counts) {
  const int z = blockIdx.z;
  const unsigned short *A, *B;
  unsigned short* O = nullptr;
  float* Of = nullptr;
  int Ka, ldo;
  int cnt = 1 << 30;
  const int* lst = nullptr;
  int Mt, Nt;
  bool gath = false;
  if (PHASE == 1) {
    Mt = 8; Nt = 11; Ka = CDIM;
    if (z < 4) {
      int zm = z >> 1, zn = z & 1;
      A = xb + (size_t)zm * 2048 * CDIM;
      B = swcat + (size_t)zn * 2816 * CDIM;
      O = hs_out + (size_t)zm * 2048 * ISDIM + (size_t)zn * 1408;
      ldo = ISDIM;
    } else {
      int e = z - 4;
      cnt = counts[e]; if (cnt > CAP) cnt = CAP;
      lst = list + e * CAP;
      gath = true;
      A = xb;
      B = wcat + (size_t)e * ICAT * CDIM;
      O = he_out + (size_t)e * CAP * IDIM;
      ldo = IDIM;
    }
  } else {
    Mt = 8; Nt = 8;
    if (z < 2) {
      Ka = ISDIM;
      A = hs + (size_t)z * 2048 * ISDIM;
      B = sw3b;
      Of = ysf + (size_t)z * 2048 * CDIM;
      ldo = CDIM;
    } else {
      int e = z - 2;
      cnt = counts[e]; if (cnt > CAP) cnt = CAP;
      Ka = IDIM;
      A = he + (size_t)e * CAP * IDIM;
      B = w3b + (size_t)e * CDIM * IDIM;
      O = eo + (size_t)e * CAP * CDIM;
      ldo = CDIM;
    }
  }
  const int wg = xcd_swizzle(blockIdx.x, Mt * Nt);
  const int mt = wg % Mt, nt = wg / Mt;
  if (mt * 256 >= cnt) return;

  __shared__ __align__(16) char lds[2][2][2][16384]; // [buf][A|B][kk][256x64B]

  const int tid = threadIdx.x;
  const int srow = tid >> 2;
  const int c16  = (tid & 3) << 4;
  const int scol = c16 ^ (((srow >> 1) & 3) << 4);
  const char* aS[2];
  const char* bS[2];
#pragma unroll
  for (int j = 0; j < 2; j++) {
    int ar = mt * 256 + j * 128 + srow;
    if (PHASE == 1 && gath) ar = (ar < cnt) ? lst[ar] : lst[0];
    aS[j] = (const char*)A + (size_t)ar * Ka * 2 + scol;
    int br = nt * 256 + j * 128 + srow;
    bS[j] = (const char*)B + (size_t)br * Ka * 2 + scol;
  }
  auto stageA = [&](int buf, int kt, int h) {
    size_t kb = (size_t)kt * 128 + (size_t)(h << 6);
    char* aD = &lds[buf][0][h][0] + tid * 16;
    GLOAD16(aS[0] + kb, aD);
    GLOAD16(aS[1] + kb, aD + 8192);
  };
  auto stageB = [&](int buf, int kt, int h) {
    size_t kb = (size_t)kt * 128 + (size_t)(h << 6);
    char* bD = &lds[buf][1][h][0] + tid * 16;
    GLOAD16(bS[0] + kb, bD);
    GLOAD16(bS[1] + kb, bD + 8192);
  };

  const int lane = tid & 63, wid = tid >> 6;
  const int wr = wid >> 2, wc = wid & 3;   // 2 x 4 wave grid, per-wave 128x64
  const int lrow = lane & 15;
  const int klane = (lane >> 4) << 4;
  const int rsw = ((lrow >> 1) & 3) << 4;
  const int aOff = (wr * 128 + lrow) * 64 + (klane ^ rsw);
  const int bOff = (wc * 64 + lrow) * 64 + (klane ^ rsw);

  f32x4 acc[8][4];
#pragma unroll
  for (int mf = 0; mf < 8; mf++)
#pragma unroll
    for (int nf = 0; nf < 4; nf++) acc[mf][nf] = (f32x4){0.f, 0.f, 0.f, 0.f};

  // prologue: (0,kk0),(0,kk1),(1,kk0) staged; drain (0,kk0) [8 newer]
  stageA(0, 0, 0); stageB(0, 0, 0);
  stageA(0, 0, 1); stageB(0, 0, 1);
  stageA(1, 1, 0); stageB(1, 1, 0);
  asm volatile("s_waitcnt vmcnt(8)" ::: "memory");
  __builtin_amdgcn_s_barrier();

#define MFMA_Q(MB)                                                             \
  _Pragma("unroll")                                                            \
  for (int nf = 0; nf < 4; nf++)                                               \
    _Pragma("unroll")                                                          \
    for (int m = 0; m < 4; m++)                                                \
      acc[(MB) * 4 + m][nf] = __builtin_amdgcn_mfma_f32_16x16x32_bf16(         \
          aR[m], bR[nf], acc[(MB) * 4 + m][nf], 0, 0, 0);

  const int ntk = Ka >> 6;
  for (int t = 0; t < ntk; t++) {
    const int p = t & 1;
    const char* aK0 = &lds[p][0][0][0];
    const char* aK1 = &lds[p][0][1][0];
    const char* bK0 = &lds[p][1][0][0];
    const char* bK1 = &lds[p][1][1][0];
    bf16x8 aR[4], bR[4];
    // ---- P1: kk0, m-half 0 -> acc[0..3]; stage A(t+1,kk1) -> buf p^1
#pragma unroll
    for (int i = 0; i < 4; i++) aR[i] = *(const bf16x8*)(aK0 + aOff + i * 1024);
#pragma unroll
    for (int i = 0; i < 4; i++) bR[i] = *(const bf16x8*)(bK0 + bOff + i * 1024);
    if (t + 1 < ntk) stageA(p ^ 1, t + 1, 1);
    __builtin_amdgcn_s_barrier();
    asm volatile("s_waitcnt lgkmcnt(0)" ::: "memory");
    __builtin_amdgcn_s_setprio(1);
    MFMA_Q(0)
    __builtin_amdgcn_s_setprio(0);
    __builtin_amdgcn_s_barrier();
    // ---- P2: kk0, m-half 1 -> acc[4..7]; stage B(t+1,kk1); drain (t,kk1)
#pragma unroll
    for (int i = 0; i < 4; i++) aR[i] = *(const bf16x8*)(aK0 + aOff + (i + 4) * 1024);
    if (t + 1 < ntk) {
      stageB(p ^ 1, t + 1, 1);
      asm volatile("s_waitcnt vmcnt(8)" ::: "memory");
    } else {
      asm volatile("s_waitcnt vmcnt(0)" ::: "memory");
    }
    __builtin_amdgcn_s_barrier();
    asm volatile("s_waitcnt lgkmcnt(0)" ::: "memory");
    __builtin_amdgcn_s_setprio(1);
    MFMA_Q(1)
    __builtin_amdgcn_s_setprio(0);
    __builtin_amdgcn_s_barrier();
    // ---- P3: kk1, m-half 0 -> acc[0..3]; stage A(t+2,kk0) -> buf p
#pragma unroll
    for (int i = 0; i < 4; i++) aR[i] = *(const bf16x8*)(aK1 + aOff + i * 1024);
#pragma unroll
    for (int i = 0; i < 4; i++) bR[i] = *(const bf16x8*)(bK1 + bOff + i * 1024);
    if (t + 2 < ntk) stageA(p, t + 2, 0);
    __builtin_amdgcn_s_barrier();
    asm volatile("s_waitcnt lgkmcnt(0)" ::: "memory");
    __builtin_amdgcn_s_setprio(1);
    MFMA_Q(0)
    __builtin_amdgcn_s_setprio(0);
    __builtin_amdgcn_s_barrier();
    // ---- P4: kk1, m-half 1 -> acc[4..7]; stage B(t+2,kk0); drain (t+1,kk0)
#pragma unroll
    for (int i = 0; i < 4; i++) aR[i] = *(const bf16x8*)(aK1 + aOff + (i + 4) * 1024);
    if (t + 2 < ntk) {
      stageB(p, t + 2, 0);
      asm volatile("s_waitcnt vmcnt(8)" ::: "memory");
    } else if (t + 1 < ntk) {
      asm volatile("s_waitcnt vmcnt(4)" ::: "memory");
    }
    __builtin_amdgcn_s_barrier();
    asm volatile("s_waitcnt lgkmcnt(0)" ::: "memory");
    __builtin_amdgcn_s_setprio(1);
    MFMA_Q(1)
    __builtin_amdgcn_s_setprio(0);
    __builtin_amdgcn_s_barrier();
  }
#undef MFMA_Q

  const int r4 = (lane >> 4) * 4;
  if (PHASE == 1) {
    // fused gate: waves wc>=2 publish h2 (f32) via XOR-swizzled LDS, wc<2 combine.
    float* ldsF = (float*)&lds[0][0][0][0];      // 256 x 128 f32 = 128 KiB
    const int rbase = wr * 128 + r4;
    if (wc >= 2) {
      const int cb = (wc - 2) * 64;
#pragma unroll
      for (int mf = 0; mf < 8; mf++)
#pragma unroll
        for (int nf = 0; nf < 4; nf++) {
          int cc = cb + nf * 16 + lrow;
#pragma unroll
          for (int r = 0; r < 4; r++) {
            int rr = rbase + mf * 16 + r;
            ldsF[rr * 128 + (cc ^ (((rr >> 2) & 1) << 4))] = acc[mf][nf][r];
          }
        }
    }
    __syncthreads();
    if (wc < 2) {
      const int cb = wc * 64;
#pragma unroll
      for (int mf = 0; mf < 8; mf++) {
        int row0 = mt * 256 + wr * 128 + mf * 16 + r4;
#pragma unroll
        for (int nf = 0; nf < 4; nf++) {
          int cc = cb + nf * 16 + lrow;
          int col = nt * 128 + cc;
#pragma unroll
          for (int r = 0; r < 4; r++) {
            int rr = rbase + mf * 16 + r;
            float z1 = acc[mf][nf][r];
            float z2 = ldsF[rr * 128 + (cc ^ (((rr >> 2) & 1) << 4))];
            float gv = z1 / (1.f + __expf(-z1)) * z2;
            O[(size_t)(row0 + r) * ldo + col] = f2bf(gv);
          }
        }
      }
    }
  } else {
    const int rowb = mt * 256 + wr * 128;
    const int colb = nt * 256 + wc * 64;
#pragma unroll
    for (int mf = 0; mf < 8; mf++) {
      int row0 = rowb + mf * 16 + r4;
#pragma unroll
      for (int nf = 0; nf < 4; nf++) {
        int col = colb + nf * 16 + lrow;
#pragma unroll
        for (int r = 0; r < 4; r++) {
          if (z < 2)
            Of[(size_t)(row0 + r) * ldo + col] = acc[mf][nf][r];
          else
            O[(size_t)(row0 + r) * ldo + col] = f2bf(acc[mf][nf][r]);
        }
      }
    }
  }
}

// ---------------- combine: y = ys + sum_k w_k * eo[slot_k] ----------------
__global__ __launch_bounds__(256) void combine_kernel(
    float* __restrict__ y, const float* __restrict__ ysf,
    const unsigned short* __restrict__ eo,
    const int* __restrict__ slot_of, const float* __restrict__ wts) {
  int idx = blockIdx.x * 256 + threadIdx.x;
  int n = idx >> 9;
  int c = (idx & 511) * 4;
  float4 v = *(const float4*)(ysf + (size_t)n * CDIM + c);
#pragma unroll
  for (int k = 0; k < 2; k++) {
    int slot = slot_of[n * 2 + k];
    float w = wts[n * 2 + k];
    ushort4 h = *(const ushort4*)(eo + (size_t)slot * CDIM + c);
    v.x += w * bf2f(h.x);
    v.y += w * bf2f(h.y);
    v.z += w * bf2f(h.z);
    v.w += w * bf2f(h.w);
  }
  *(float4*)(y + (size_t)n * CDIM + c) = v;
}

extern "C" void kernel_launch(void* const* d_in, const int* in_sizes, int n_in,
                              void* d_out, int out_size, void* d_ws, size_t ws_size,
                              hipStream_t stream) {
  const float* x   = (const float*)d_in[0];
  const float* gw  = (const float*)d_in[1];
  const float* w1  = (const float*)d_in[2];
  const float* w2  = (const float*)d_in[3];
  const float* w3  = (const float*)d_in[4];
  const float* sw1 = (const float*)d_in[5];
  const float* sw2 = (const float*)d_in[6];
  const float* sw3 = (const float*)d_in[7];
  float* y = (float*)d_out;

  char* ws = (char*)d_ws;
  size_t off = 0;
  auto alloc = [&](size_t b) -> void* {
    void* p = ws + off;
    off += (b + 255) & ~(size_t)255;
    return p;
  };
  unsigned short* xb    = (unsigned short*)alloc((size_t)N_TOK * CDIM * 2);
  unsigned short* wcat  = (unsigned short*)alloc((size_t)NEXP * ICAT * CDIM * 2);
  unsigned short* w3b   = (unsigned short*)alloc((size_t)NEXP * CDIM * IDIM * 2);
  unsigned short* swcat = (unsigned short*)alloc((size_t)SCAT * CDIM * 2);
  unsigned short* sw3b  = (unsigned short*)alloc((size_t)CDIM * ISDIM * 2);
  unsigned short* hs    = (unsigned short*)alloc((size_t)N_TOK * ISDIM * 2);
  unsigned short* he    = (unsigned short*)alloc((size_t)NEXP * CAP * IDIM * 2);
  float*          ysf   = (float*)alloc((size_t)N_TOK * CDIM * 4);
  int*   counts  = (int*)alloc(NEXP * 4);
  int*   list    = (int*)alloc((size_t)NEXP * CAP * 4);
  int*   slot_of = (int*)alloc((size_t)N_TOK * 2 * 4);
  float* wtsb    = (float*)alloc((size_t)N_TOK * 2 * 4);
  // alias: eo reuses wcat (dead after fc GEMM)
  unsigned short* eoB = wcat;

  hipMemsetAsync(counts, 0, NEXP * 4, stream);
  routing_kernel<<<N_TOK, 64, 0, stream>>>(x, gw, counts, list, slot_of, wtsb);

  cvt_all<<<46336, 256, 0, stream>>>(x, w1, w2, w3, sw1, sw2, sw3,
                                     xb, wcat, w3b, swcat, sw3b);

  // fc GEMM with fused silu-gate epilogue
  moe_gemm<1><<<dim3(88, 1, 12), 512, 0, stream>>>(
      xb, swcat, wcat, hs, he, hs, sw3b, he, w3b, ysf, eoB, list, counts);

  // proj GEMM: z 0..1 shared (long K first), z 2..9 experts
  moe_gemm<2><<<dim3(64, 1, 10), 512, 0, stream>>>(
      xb, swcat, wcat, hs, he, hs, sw3b, he, w3b, ysf, eoB, list, counts);

  // combine
  combine_kernel<<<(N_TOK * (CDIM / 4)) / 256, 256, 0, stream>>>(y, ysf, eoB, slot_of, wtsb);
}